// Round 1
// 1645.832 us; speedup vs baseline: 3.6529x; 3.6529x over previous
//
#include <hip/hip_runtime.h>
#include <hip/hip_bf16.h>

// ---------------------------------------------------------------------------
// Transformer block on MI355X. B=2, T=2048, H=2048, QH=16, KH=8, D=128, F=8192
// Outputs concatenated in d_out as FLOAT32: x | k | v
// Round 5 -> 6: rocprof showed gemm_bt with VGPR_Count=60 and WRITE_SIZE
// ~1.85 GB/dispatch -> acc[4][4] was living in SCRATCH (runtime-indexed
// ext_vector array + runtime `mode` branch in epilogue, guide rule #20).
// Fix: template the GEMMs on MODE (if constexpr epilogue) + #pragma unroll
// every loop that indexes vector-register arrays (gemm epilogues, flash-attn
// oacc/sacc loops). All launches updated to the templated instantiations.
// ---------------------------------------------------------------------------

#define Bc  2
#define Tc  2048
#define Hc  2048
#define QHc 16
#define KHc 8
#define Dc  128
#define Fc  8192
#define Mc  (Bc*Tc)          // 4096 rows
#define FCHUNK 2048          // MLP F-chunk (4 chunks)
#define EPSc 1e-6f
#define MASKVAL (-1e30f)

typedef __bf16  bf16x8 __attribute__((ext_vector_type(8)));
typedef short   short8 __attribute__((ext_vector_type(8)));
typedef float   f32x4  __attribute__((ext_vector_type(4)));

// ---------------- reductions -------------------------------------------------
__device__ __forceinline__ float waveReduceSum(float v) {
    for (int off = 32; off > 0; off >>= 1) v += __shfl_down(v, off, 64);
    return v;
}

// ---------------- async global->LDS 16B helper -------------------------------
__device__ __forceinline__ void load_lds_16(const __hip_bfloat16* g,
                                            __hip_bfloat16* l) {
    __builtin_amdgcn_global_load_lds(
        (const __attribute__((address_space(1))) void*)g,
        (__attribute__((address_space(3))) void*)l, 16, 0, 0);
}

// ---------------- RMSNorm over f32 rows -> bf16 ------------------------------
__global__ __launch_bounds__(256) void rmsnorm_f32_kernel(
    const float* __restrict__ in, const float* __restrict__ gamma,
    __hip_bfloat16* __restrict__ out, int width)
{
    const int row = blockIdx.x;
    const float* r = in + (size_t)row * width;
    float ss = 0.f;
    for (int i = threadIdx.x; i < width; i += 256) { float v = r[i]; ss += v * v; }
    ss = waveReduceSum(ss);
    __shared__ float red[4];
    if ((threadIdx.x & 63) == 0) red[threadIdx.x >> 6] = ss;
    __syncthreads();
    const float tot = red[0] + red[1] + red[2] + red[3];
    const float inv = 1.0f / sqrtf(tot / (float)width + EPSc);
    __hip_bfloat16* o = out + (size_t)row * width;
    for (int i = threadIdx.x; i < width; i += 256)
        o[i] = __float2bfloat16(gamma[i] * r[i] * inv);
}

// ---------------- fused per-head RMSNorm (D=128) + RoPE ----------------------
__global__ __launch_bounds__(128) void qknorm_rope_kernel(
    const __hip_bfloat16* in, const float* __restrict__ gamma,
    const float* __restrict__ sinp, const float* __restrict__ cosp,
    __hip_bfloat16* outB, float* outF, int heads)
{
    const int row = blockIdx.x;            // (b*T + t)*heads + h
    const int bt  = row / heads;           // b*T + t
    const int d   = threadIdx.x;           // 0..127
    const float v = __bfloat162float(in[(size_t)row * Dc + d]);
    float ss = waveReduceSum(v * v);
    __shared__ float red[2];
    __shared__ float nrm[Dc];
    if ((d & 63) == 0) red[d >> 6] = ss;
    __syncthreads();
    const float rms = sqrtf((red[0] + red[1]) * (1.0f / (float)Dc) + EPSc);
    const float xn = __bfloat162float(__float2bfloat16(gamma[d] * v / rms));
    nrm[d] = xn;
    __syncthreads();
    float res;
    if (d < 64) {
        const float s = sinp[(size_t)bt * 64 + d];
        const float c = cosp[(size_t)bt * 64 + d];
        res = nrm[d] * c - nrm[d + 64] * s;
    } else {
        const float s = sinp[(size_t)bt * 64 + (d - 64)];
        const float c = cosp[(size_t)bt * 64 + (d - 64)];
        res = nrm[d] * c + nrm[d - 64] * s;
    }
    outB[(size_t)row * Dc + d] = __float2bfloat16(res);
    if (outF) outF[(size_t)row * Dc + d] = res;   // un-rounded f32 (ref k dtype)
}

// ---------------- weight convert+transpose: W f32[K][N] -> Wt bf16[N][K] -----
__global__ __launch_bounds__(256) void convert_transpose_kernel(
    const float* __restrict__ W, __hip_bfloat16* __restrict__ Wt, int K, int N)
{
    __shared__ float tile[32][33];
    const int tx = threadIdx.x & 31;
    const int ty = threadIdx.x >> 5;       // 0..7
    const int n0 = blockIdx.x * 32;
    const int k0 = blockIdx.y * 32;
    for (int r = 0; r < 4; ++r) {
        const int k = ty + r * 8;
        tile[k][tx] = W[(size_t)(k0 + k) * N + n0 + tx];
    }
    __syncthreads();
    for (int r = 0; r < 4; ++r) {
        const int n = ty + r * 8;
        Wt[(size_t)(n0 + n) * K + k0 + tx] = __float2bfloat16(tile[tx][n]);
    }
}

// ---------------- fast bf16 GEMM (B^T weights, global_load_lds staging) ------
// C[M,N] = A[M,K](bf16, lda) @ Bt[N,K]^T (bf16, ldt). 128x128 tile, BK=32.
// MODE (compile time): 0 bf16 out; 1 f32 resid+bf16(acc); 3 silu-mul; 4 dual.
template <int MODE>
__global__ __launch_bounds__(256) void gemm_bt_kernel(
    const __hip_bfloat16* __restrict__ A, const __hip_bfloat16* __restrict__ Bt,
    __hip_bfloat16* outB, float* outF, const float* resid,
    const __hip_bfloat16* gmul, int M, int N, int K, int lda, int ldt)
{
    __shared__ __hip_bfloat16 As[128 * 32];     // [m][k], 8 KB, no pad
    __shared__ __hip_bfloat16 Bs[128 * 32];     // [n][k], 8 KB, no pad

    const int tid  = threadIdx.x;
    const int lane = tid & 63;
    const int wave = tid >> 6;
    const int l15  = lane & 15;
    const int quad = lane >> 4;
    const int q8   = quad * 8;
    const int wm   = wave >> 1;
    const int wn   = wave & 1;
    const int m0   = blockIdx.y * 128;
    const int n0   = blockIdx.x * 128;

    // staging chunks: chunk c covers row c>>2, k-offset (c&3)*8 (16 B each)
    const int c0 = tid, c1 = tid + 256;
    const int r0 = c0 >> 2, o0 = (c0 & 3) * 8;
    const int r1 = c1 >> 2, o1 = (c1 & 3) * 8;
    const __hip_bfloat16* gA0 = A + (size_t)(m0 + r0) * lda + o0;
    const __hip_bfloat16* gA1 = A + (size_t)(m0 + r1) * lda + o1;
    const __hip_bfloat16* gB0 = Bt + (size_t)(n0 + r0) * ldt + o0;
    const __hip_bfloat16* gB1 = Bt + (size_t)(n0 + r1) * ldt + o1;

    f32x4 acc[4][4];
    const f32x4 zero = {0.f, 0.f, 0.f, 0.f};
#pragma unroll
    for (int i = 0; i < 4; ++i)
#pragma unroll
        for (int j = 0; j < 4; ++j) acc[i][j] = zero;

    for (int k0 = 0; k0 < K; k0 += 32) {
        __syncthreads();                        // protect LDS from prev reads
        load_lds_16(gA0 + k0, As + c0 * 8);
        load_lds_16(gA1 + k0, As + c1 * 8);
        load_lds_16(gB0 + k0, Bs + c0 * 8);
        load_lds_16(gB1 + k0, Bs + c1 * 8);
        __syncthreads();                        // waits vmcnt(0) -> LDS ready

        bf16x8 af[4], bfv[4];
#pragma unroll
        for (int mt = 0; mt < 4; ++mt)
            af[mt] = *reinterpret_cast<const bf16x8*>(
                As + (wm * 64 + mt * 16 + l15) * 32 + q8);
#pragma unroll
        for (int nt = 0; nt < 4; ++nt)
            bfv[nt] = *reinterpret_cast<const bf16x8*>(
                Bs + (wn * 64 + nt * 16 + l15) * 32 + q8);
#pragma unroll
        for (int mt = 0; mt < 4; ++mt)
#pragma unroll
            for (int nt = 0; nt < 4; ++nt)
                acc[mt][nt] = __builtin_amdgcn_mfma_f32_16x16x32_bf16(
                    af[mt], bfv[nt], acc[mt][nt], 0, 0, 0);
    }

    // ---- epilogue: D layout col=lane&15, row=quad*4+reg ---------------------
    // Fully unrolled + compile-time MODE => every acc[][] access is static,
    // so the accumulator stays in registers (no scratch).
#pragma unroll
    for (int mt = 0; mt < 4; ++mt) {
#pragma unroll
        for (int nt = 0; nt < 4; ++nt) {
            const f32x4 a  = acc[mt][nt];
            const int col  = n0 + wn * 64 + nt * 16 + l15;
            const int rowb = m0 + wm * 64 + mt * 16 + quad * 4;
#pragma unroll
            for (int r = 0; r < 4; ++r) {
                const size_t idx = (size_t)(rowb + r) * N + col;
                const float val = a[r];
                if constexpr (MODE == 0) {
                    outB[idx] = __float2bfloat16(val);
                } else if constexpr (MODE == 1) {
                    outF[idx] = resid[idx] +
                                __bfloat162float(__float2bfloat16(val));
                } else if constexpr (MODE == 3) {
                    const float g = __bfloat162float(gmul[idx]);
                    const float sil = __bfloat162float(
                        __float2bfloat16(g / (1.f + __expf(-g))));
                    const float u = __bfloat162float(__float2bfloat16(val));
                    outB[idx] = __float2bfloat16(sil * u);
                } else { // MODE 4
                    const __hip_bfloat16 b = __float2bfloat16(val);
                    outB[idx] = b;
                    outF[idx] = __bfloat162float(b);
                }
            }
        }
    }
}

// ---------------- slow-path GEMM (f32 weights) — ws fallback -----------------
template <int MODE>
__global__ __launch_bounds__(256) void gemm_kernel(
    const __hip_bfloat16* __restrict__ A, const float* __restrict__ Bw,
    __hip_bfloat16* outB, float* outF, const float* resid,
    const __hip_bfloat16* gmul, int M, int N, int K, int ldb)
{
    __shared__ __hip_bfloat16 As[128][32];
    __shared__ __hip_bfloat16 Bs[128][40];

    const int tid  = threadIdx.x;
    const int lane = tid & 63;
    const int wave = tid >> 6;
    const int l15  = lane & 15;
    const int quad = lane >> 4;
    const int q8   = quad * 8;
    const int wm   = wave >> 1;
    const int wn   = wave & 1;
    const int m0   = blockIdx.y * 128;
    const int n0   = blockIdx.x * 128;

    f32x4 acc[4][4];
    const f32x4 zero = {0.f, 0.f, 0.f, 0.f};
#pragma unroll
    for (int i = 0; i < 4; ++i)
#pragma unroll
        for (int j = 0; j < 4; ++j) acc[i][j] = zero;

    const int nK = K >> 5;
    for (int kt = 0; kt < nK; ++kt) {
        const int k0 = kt << 5;
        __syncthreads();
#pragma unroll
        for (int vv = 0; vv < 2; ++vv) {
            const int vi  = vv * 256 + tid;
            const int row = vi >> 2;
            const int col = (vi & 3) * 8;
            *(short8*)(&As[row][col]) =
                *(const short8*)(A + (size_t)(m0 + row) * K + k0 + col);
        }
        {
            const int n  = tid & 127;
            const int kk = tid >> 7;
            const float* bp = Bw + (size_t)k0 * ldb + n0 + n;
#pragma unroll
            for (int p = 0; p < 16; ++p) {
                const int k = p * 2 + kk;
                Bs[n][k] = __float2bfloat16(bp[(size_t)k * ldb]);
            }
        }
        __syncthreads();
        bf16x8 af[4], bfv[4];
#pragma unroll
        for (int mt = 0; mt < 4; ++mt)
            af[mt] = *reinterpret_cast<const bf16x8*>(&As[wm * 64 + mt * 16 + l15][q8]);
#pragma unroll
        for (int nt = 0; nt < 4; ++nt)
            bfv[nt] = *reinterpret_cast<const bf16x8*>(&Bs[wn * 64 + nt * 16 + l15][q8]);
#pragma unroll
        for (int mt = 0; mt < 4; ++mt)
#pragma unroll
            for (int nt = 0; nt < 4; ++nt)
                acc[mt][nt] = __builtin_amdgcn_mfma_f32_16x16x32_bf16(
                    af[mt], bfv[nt], acc[mt][nt], 0, 0, 0);
    }

#pragma unroll
    for (int mt = 0; mt < 4; ++mt) {
#pragma unroll
        for (int nt = 0; nt < 4; ++nt) {
            const f32x4 a  = acc[mt][nt];
            const int col  = n0 + wn * 64 + nt * 16 + l15;
            const int rowb = m0 + wm * 64 + mt * 16 + quad * 4;
#pragma unroll
            for (int r = 0; r < 4; ++r) {
                const size_t idx = (size_t)(rowb + r) * N + col;
                const float val = a[r];
                if constexpr (MODE == 0) {
                    outB[idx] = __float2bfloat16(val);
                } else if constexpr (MODE == 1) {
                    outF[idx] = resid[idx] +
                                __bfloat162float(__float2bfloat16(val));
                } else if constexpr (MODE == 3) {
                    const float g = __bfloat162float(gmul[idx]);
                    const float sil = __bfloat162float(
                        __float2bfloat16(g / (1.f + __expf(-g))));
                    const float u = __bfloat162float(__float2bfloat16(val));
                    outB[idx] = __float2bfloat16(sil * u);
                } else {
                    const __hip_bfloat16 b = __float2bfloat16(val);
                    outB[idx] = b;
                    outF[idx] = __bfloat162float(b);
                }
            }
        }
    }
}

// ---------------- MFMA flash attention (loops hardened with unroll) ----------
__global__ __launch_bounds__(256) void flash_attn_kernel(
    const __hip_bfloat16* q, const __hip_bfloat16* __restrict__ k,
    const __hip_bfloat16* __restrict__ v, const int* __restrict__ mask,
    __hip_bfloat16* out)
{
    __shared__ unsigned short Ks[64][136];
    __shared__ unsigned short Vs[128][72];
    __shared__ unsigned short Ps[4][16][72];
    __shared__ int msk[64];

    const int tid  = threadIdx.x;
    const int lane = tid & 63;
    const int wave = tid >> 6;
    const int l15  = lane & 15;
    const int quad = lane >> 4;
    const int q0   = blockIdx.x * 64;
    const int bh   = blockIdx.y;
    const int b    = bh >> 4;
    const int h    = bh & 15;
    const int kh   = h >> 1;

    const float scale = 0.08838834764831845f;

    bf16x8 qf[4];
    {
        const __hip_bfloat16* qp =
            q + (((size_t)(b * Tc + q0 + wave * 16 + l15)) * QHc + h) * Dc;
#pragma unroll
        for (int kk = 0; kk < 4; ++kk)
            qf[kk] = *(const bf16x8*)(qp + kk * 32 + quad * 8);
    }

    float mrow[4] = {MASKVAL, MASKVAL, MASKVAL, MASKVAL};
    float lrow[4] = {0.f, 0.f, 0.f, 0.f};
    f32x4 oacc[8];
#pragma unroll
    for (int i = 0; i < 8; ++i) oacc[i] = (f32x4){0.f, 0.f, 0.f, 0.f};

    const int ktmax = q0 >> 6;
    for (int kt = 0; kt <= ktmax; ++kt) {
        const int kvbase = kt * 64;
        __syncthreads();
#pragma unroll
        for (int i = 0; i < 4; ++i) {
            const int c  = i * 256 + tid;
            const int kv = c >> 4;
            const int d0 = (c & 15) * 8;
            *(bf16x8*)(&Ks[kv][d0]) = *(const bf16x8*)(
                k + (((size_t)(b * Tc + kvbase + kv)) * KHc + kh) * Dc + d0);
        }
        {
            const int kv = tid & 63;
            const int g0 = (tid >> 6) * 4;
            for (int g = g0; g < g0 + 4; ++g) {
                const int d0 = g * 8;
                const short8 tmp = *(const short8*)(
                    v + (((size_t)(b * Tc + kvbase + kv)) * KHc + kh) * Dc + d0);
#pragma unroll
                for (int j = 0; j < 8; ++j)
                    Vs[d0 + j][kv] = (unsigned short)tmp[j];
            }
        }
        if (tid < 64) msk[tid] = mask[b * Tc + kvbase + tid];
        __syncthreads();

        f32x4 sacc[4];
#pragma unroll
        for (int nt = 0; nt < 4; ++nt) sacc[nt] = (f32x4){0.f, 0.f, 0.f, 0.f};
#pragma unroll
        for (int nt = 0; nt < 4; ++nt)
#pragma unroll
            for (int kk = 0; kk < 4; ++kk) {
                const bf16x8 kf = *(const bf16x8*)(&Ks[nt * 16 + l15][kk * 32 + quad * 8]);
                sacc[nt] = __builtin_amdgcn_mfma_f32_16x16x32_bf16(
                    qf[kk], kf, sacc[nt], 0, 0, 0);
            }

        float tmax[4] = {MASKVAL, MASKVAL, MASKVAL, MASKVAL};
#pragma unroll
        for (int nt = 0; nt < 4; ++nt) {
            const int kvpos  = kvbase + nt * 16 + l15;
            const bool kvld  = (msk[nt * 16 + l15] != 0);
#pragma unroll
            for (int r = 0; r < 4; ++r) {
                const int qr = q0 + wave * 16 + quad * 4 + r;
                float s = sacc[nt][r] * scale;
                s = (kvld && kvpos <= qr) ? s : MASKVAL;
                sacc[nt][r] = s;
                tmax[r] = fmaxf(tmax[r], s);
            }
        }
#pragma unroll
        for (int r = 0; r < 4; ++r)
            for (int off = 1; off < 16; off <<= 1)
                tmax[r] = fmaxf(tmax[r], __shfl_xor(tmax[r], off, 64));

        float alpha[4];
#pragma unroll
        for (int r = 0; r < 4; ++r) {
            const float mnew = fmaxf(mrow[r], tmax[r]);
            alpha[r] = __expf(mrow[r] - mnew);
            mrow[r]  = mnew;
        }
        float tsum[4] = {0.f, 0.f, 0.f, 0.f};
#pragma unroll
        for (int nt = 0; nt < 4; ++nt)
#pragma unroll
            for (int r = 0; r < 4; ++r) {
                const float p = __expf(sacc[nt][r] - mrow[r]);
                sacc[nt][r] = p;
                tsum[r] += p;
            }
#pragma unroll
        for (int r = 0; r < 4; ++r)
            for (int off = 1; off < 16; off <<= 1)
                tsum[r] += __shfl_xor(tsum[r], off, 64);
#pragma unroll
        for (int r = 0; r < 4; ++r)
            lrow[r] = lrow[r] * alpha[r] + tsum[r];

#pragma unroll
        for (int nt = 0; nt < 4; ++nt)
#pragma unroll
            for (int r = 0; r < 4; ++r) {
                const __hip_bfloat16 pb = __float2bfloat16(sacc[nt][r]);
                Ps[wave][quad * 4 + r][nt * 16 + l15] =
                    *(const unsigned short*)&pb;
            }
        __syncthreads();

#pragma unroll
        for (int ntd = 0; ntd < 8; ++ntd)
#pragma unroll
            for (int r = 0; r < 4; ++r) oacc[ntd][r] *= alpha[r];
        bf16x8 pa[2];
#pragma unroll
        for (int kk2 = 0; kk2 < 2; ++kk2)
            pa[kk2] = *(const bf16x8*)(&Ps[wave][l15][kk2 * 32 + quad * 8]);
#pragma unroll
        for (int ntd = 0; ntd < 8; ++ntd)
#pragma unroll
            for (int kk2 = 0; kk2 < 2; ++kk2) {
                const bf16x8 vf = *(const bf16x8*)(
                    &Vs[ntd * 16 + l15][kk2 * 32 + quad * 8]);
                oacc[ntd] = __builtin_amdgcn_mfma_f32_16x16x32_bf16(
                    pa[kk2], vf, oacc[ntd], 0, 0, 0);
            }
    }

#pragma unroll
    for (int ntd = 0; ntd < 8; ++ntd)
#pragma unroll
        for (int r = 0; r < 4; ++r) {
            const float li = lrow[r];
            const float o  = (li > 0.f) ? oacc[ntd][r] / li : 0.f;
            const int qr   = q0 + wave * 16 + quad * 4 + r;
            out[(((size_t)(b * Tc + qr)) * QHc + h) * Dc + ntd * 16 + l15] =
                __float2bfloat16(o);
        }
}

// ---------------------------------------------------------------------------
extern "C" void kernel_launch(void* const* d_in, const int* in_sizes, int n_in,
                              void* d_out, int out_size, void* d_ws, size_t ws_size,
                              hipStream_t stream) {
    const float* x          = (const float*)d_in[0];
    const float* sinp       = (const float*)d_in[1];
    const float* cosp       = (const float*)d_in[2];
    const int*   token_mask = (const int*)d_in[3];
    const float* pre_gamma  = (const float*)d_in[5];
    const float* wq         = (const float*)d_in[6];
    const float* wk         = (const float*)d_in[7];
    const float* wv         = (const float*)d_in[8];
    const float* q_gamma    = (const float*)d_in[9];
    const float* k_gamma    = (const float*)d_in[10];
    const float* wo         = (const float*)d_in[11];
    const float* post_gamma = (const float*)d_in[12];
    const float* wg         = (const float*)d_in[13];
    const float* wu         = (const float*)d_in[14];
    const float* wd         = (const float*)d_in[15];

    // d_out sections, ALL FLOAT32: x | k | v
    float* outx = (float*)d_out;
    float* outk = outx + (size_t)Bc * Tc * Hc;
    float* outv = outk + (size_t)Bc * Tc * KHc * Dc;

    const bool fast = (ws_size >= 176160768ull);

    if (fast) {
        // ---- fast path: bf16 transposed weights in ws -----------------------
        char* w = (char*)d_ws;
        __hip_bfloat16* wq_t  = (__hip_bfloat16*)(w);               //  8.39 MB
        __hip_bfloat16* wk_t  = (__hip_bfloat16*)(w + 8388608);     //  4.19 MB
        __hip_bfloat16* wv_t  = (__hip_bfloat16*)(w + 12582912);    //  4.19 MB
        __hip_bfloat16* wo_t  = (__hip_bfloat16*)(w + 16777216);    //  8.39 MB
        __hip_bfloat16* wg_t  = (__hip_bfloat16*)(w + 25165824);    // 33.55 MB
        __hip_bfloat16* wu_t  = (__hip_bfloat16*)(w + 58720256);    // 33.55 MB
        __hip_bfloat16* wd_t  = (__hip_bfloat16*)(w + 92274688);    // 33.55 MB
        __hip_bfloat16* xnorm = (__hip_bfloat16*)(w + 125829120);   // 16.78 MB
        __hip_bfloat16* qbuf  = (__hip_bfloat16*)(w + 142606336);   // 16.78 MB
        __hip_bfloat16* kbuf  = (__hip_bfloat16*)(w + 159383552);   //  8.39 MB
        __hip_bfloat16* vbuf  = (__hip_bfloat16*)(w + 167772160);   //  8.39 MB
        __hip_bfloat16* Gtmp  = qbuf;

        // 0. convert+transpose all weights (f32 [K][N] -> bf16 [N][K])
        convert_transpose_kernel<<<dim3(Hc/32, Hc/32), 256, 0, stream>>>(wq, wq_t, Hc, Hc);
        convert_transpose_kernel<<<dim3((KHc*Dc)/32, Hc/32), 256, 0, stream>>>(wk, wk_t, Hc, KHc*Dc);
        convert_transpose_kernel<<<dim3((KHc*Dc)/32, Hc/32), 256, 0, stream>>>(wv, wv_t, Hc, KHc*Dc);
        convert_transpose_kernel<<<dim3(Hc/32, Hc/32), 256, 0, stream>>>(wo, wo_t, Hc, Hc);
        convert_transpose_kernel<<<dim3(Fc/32, Hc/32), 256, 0, stream>>>(wg, wg_t, Hc, Fc);
        convert_transpose_kernel<<<dim3(Fc/32, Hc/32), 256, 0, stream>>>(wu, wu_t, Hc, Fc);
        convert_transpose_kernel<<<dim3(Hc/32, Fc/32), 256, 0, stream>>>(wd, wd_t, Fc, Hc);

        // 1. pre-RMSNorm
        rmsnorm_f32_kernel<<<Mc, 256, 0, stream>>>(x, pre_gamma, xnorm, Hc);

        // 2-4. QKV projections
        gemm_bt_kernel<0><<<dim3(Hc/128, Mc/128), 256, 0, stream>>>(
            xnorm, wq_t, qbuf, nullptr, nullptr, nullptr, Mc, Hc, Hc, Hc, Hc);
        gemm_bt_kernel<0><<<dim3((KHc*Dc)/128, Mc/128), 256, 0, stream>>>(
            xnorm, wk_t, kbuf, nullptr, nullptr, nullptr, Mc, KHc*Dc, Hc, Hc, Hc);
        gemm_bt_kernel<4><<<dim3((KHc*Dc)/128, Mc/128), 256, 0, stream>>>(
            xnorm, wv_t, vbuf, outv, nullptr, nullptr, Mc, KHc*Dc, Hc, Hc, Hc);

        // 5-6. per-head RMSNorm + RoPE
        qknorm_rope_kernel<<<Mc*QHc, 128, 0, stream>>>(
            qbuf, q_gamma, sinp, cosp, qbuf, nullptr, QHc);
        qknorm_rope_kernel<<<Mc*KHc, 128, 0, stream>>>(
            kbuf, k_gamma, sinp, cosp, kbuf, outk, KHc);

        // 7. MFMA flash attention
        flash_attn_kernel<<<dim3(Tc/64, Bc*QHc), 256, 0, stream>>>(
            qbuf, kbuf, vbuf, token_mask, qbuf);

        // 8. wo projection + residual -> outx
        gemm_bt_kernel<1><<<dim3(Hc/128, Mc/128), 256, 0, stream>>>(
            qbuf, wo_t, nullptr, outx, x, nullptr, Mc, Hc, Hc, Hc, Hc);

        // 9. post-RMSNorm
        rmsnorm_f32_kernel<<<Mc, 256, 0, stream>>>(outx, post_gamma, xnorm, Hc);

        // 10. MLP in 4 F-chunks of 2048
        for (int c = 0; c < 4; ++c) {
            const __hip_bfloat16* wg_c = wg_t + (size_t)c * FCHUNK * Hc; // rows
            const __hip_bfloat16* wu_c = wu_t + (size_t)c * FCHUNK * Hc; // rows
            const __hip_bfloat16* wd_c = wd_t + (size_t)c * FCHUNK;      // cols
            gemm_bt_kernel<0><<<dim3(FCHUNK/128, Mc/128), 256, 0, stream>>>(
                xnorm, wg_c, Gtmp, nullptr, nullptr, nullptr,
                Mc, FCHUNK, Hc, Hc, Hc);
            gemm_bt_kernel<3><<<dim3(FCHUNK/128, Mc/128), 256, 0, stream>>>(
                xnorm, wu_c, Gtmp, nullptr, nullptr, Gtmp,
                Mc, FCHUNK, Hc, Hc, Hc);
            gemm_bt_kernel<1><<<dim3(Hc/128, Mc/128), 256, 0, stream>>>(
                Gtmp, wd_c, nullptr, outx, outx, nullptr,
                Mc, Hc, FCHUNK, FCHUNK, Fc);
        }
    } else {
        // ---- fallback: f32-weight path (48 MB ws) ---------------------------
        char* w = (char*)d_ws;
        __hip_bfloat16* xnorm = (__hip_bfloat16*)(w);
        __hip_bfloat16* qbuf  = (__hip_bfloat16*)(w + 16777216);
        __hip_bfloat16* kbuf  = (__hip_bfloat16*)(w + 33554432);
        __hip_bfloat16* vbuf  = (__hip_bfloat16*)(w + 41943040);
        __hip_bfloat16* Gtmp  = qbuf;

        rmsnorm_f32_kernel<<<Mc, 256, 0, stream>>>(x, pre_gamma, xnorm, Hc);
        gemm_kernel<0><<<dim3(Hc/128, Mc/128), 256, 0, stream>>>(
            xnorm, wq, qbuf, nullptr, nullptr, nullptr, Mc, Hc, Hc, Hc);
        gemm_kernel<0><<<dim3((KHc*Dc)/128, Mc/128), 256, 0, stream>>>(
            xnorm, wk, kbuf, nullptr, nullptr, nullptr, Mc, KHc*Dc, Hc, KHc*Dc);
        gemm_kernel<4><<<dim3((KHc*Dc)/128, Mc/128), 256, 0, stream>>>(
            xnorm, wv, vbuf, outv, nullptr, nullptr, Mc, KHc*Dc, Hc, KHc*Dc);
        qknorm_rope_kernel<<<Mc*QHc, 128, 0, stream>>>(
            qbuf, q_gamma, sinp, cosp, qbuf, nullptr, QHc);
        qknorm_rope_kernel<<<Mc*KHc, 128, 0, stream>>>(
            kbuf, k_gamma, sinp, cosp, kbuf, outk, KHc);
        flash_attn_kernel<<<dim3(Tc/64, Bc*QHc), 256, 0, stream>>>(
            qbuf, kbuf, vbuf, token_mask, qbuf);
        gemm_kernel<1><<<dim3(Hc/128, Mc/128), 256, 0, stream>>>(
            qbuf, wo, nullptr, outx, x, nullptr, Mc, Hc, Hc, Hc);
        rmsnorm_f32_kernel<<<Mc, 256, 0, stream>>>(outx, post_gamma, xnorm, Hc);
        for (int c = 0; c < 4; ++c) {
            const float* wg_c = wg + (size_t)c * FCHUNK;
            const float* wu_c = wu + (size_t)c * FCHUNK;
            const float* wd_c = wd + (size_t)c * FCHUNK * Hc;
            gemm_kernel<0><<<dim3(FCHUNK/128, Mc/128), 256, 0, stream>>>(
                xnorm, wg_c, Gtmp, nullptr, nullptr, nullptr, Mc, FCHUNK, Hc, Fc);
            gemm_kernel<3><<<dim3(FCHUNK/128, Mc/128), 256, 0, stream>>>(
                xnorm, wu_c, Gtmp, nullptr, nullptr, Gtmp, Mc, FCHUNK, Hc, Fc);
            gemm_kernel<1><<<dim3(Hc/128, Mc/128), 256, 0, stream>>>(
                Gtmp, wd_c, nullptr, outx, outx, nullptr, Mc, Hc, FCHUNK, Hc);
        }
    }
}

// Round 2
// 1381.304 us; speedup vs baseline: 4.3524x; 1.1915x over previous
//
#include <hip/hip_runtime.h>
#include <hip/hip_bf16.h>

// ---------------------------------------------------------------------------
// Transformer block on MI355X. B=2, T=2048, H=2048, QH=16, KH=8, D=128, F=8192
// Outputs concatenated in d_out as FLOAT32: x | k | v
// Round 6 -> 7: GEMM aggregate (~1300us of 1646) moved from the m97 128x128
// structure (~450 TF at these shapes) to the 256x256 8-phase counted-vmcnt
// template (T2+T3+T4+T5). MLP restructured from 4 F-chunks of 2048 to 2
// half-F passes of 4096 (Gbig = qbuf|kbuf|vbuf = 33.55MB, free after attn)
// so wg/wu run at 256 WGs (full GPU). wk/wv (N=1024) stay on the 128^2 kernel.
//
// gemm256 ledger (derived, documented for future rounds):
//   tiles t: buf=t&1. A LDS rows reordered: unit0 = m-rows {0..63}u{128..191}
//   (mg0 of both wm), unit1 = mg1 rows. B LDS linear (whole B read in P1).
//   Per tile group P1..P4: P1 reads A(mg0,ks0)+ALL B (12 ds_read), P2 A(mg0,ks1),
//   P3 A(mg1,ks0), P4 A(mg1,ks1). Dead: B after P1, A-u0 after P2, A-u1 after P4.
//   Stage schedule (iter i = tiles 2i,2i+1): Ph1:A1(2i+1) Ph2:B0(2i+2)
//   Ph3:B1(2i+2) Ph4:A0(2i+2) Ph5:A1(2i+2) Ph6:B0(2i+3) Ph7:B1(2i+3) Ph8:A0(2i+3).
//   Gates: vmcnt(6) at end of Ph4 and Ph8 (before end barrier) — forces all
//   units older than the newest 3 landed; barrier makes it cross-wave.
//   Swizzle: 16B-chunk index cc' = cc ^ (row&7), applied on global SOURCE at
//   stage time (DMA dest stays linear) and on ds_read address (rule #21).
// ---------------------------------------------------------------------------

#define Bc  2
#define Tc  2048
#define Hc  2048
#define QHc 16
#define KHc 8
#define Dc  128
#define Fc  8192
#define Mc  (Bc*Tc)          // 4096 rows
#define FCHUNK 2048          // fallback MLP F-chunk
#define EPSc 1e-6f
#define MASKVAL (-1e30f)

typedef __bf16  bf16x8 __attribute__((ext_vector_type(8)));
typedef short   short8 __attribute__((ext_vector_type(8)));
typedef float   f32x4  __attribute__((ext_vector_type(4)));

// ---------------- reductions -------------------------------------------------
__device__ __forceinline__ float waveReduceSum(float v) {
    for (int off = 32; off > 0; off >>= 1) v += __shfl_down(v, off, 64);
    return v;
}

// ---------------- async global->LDS 16B helper -------------------------------
__device__ __forceinline__ void load_lds_16(const __hip_bfloat16* g,
                                            __hip_bfloat16* l) {
    __builtin_amdgcn_global_load_lds(
        (const __attribute__((address_space(1))) void*)g,
        (__attribute__((address_space(3))) void*)l, 16, 0, 0);
}

// ---------------- RMSNorm over f32 rows -> bf16 ------------------------------
__global__ __launch_bounds__(256) void rmsnorm_f32_kernel(
    const float* __restrict__ in, const float* __restrict__ gamma,
    __hip_bfloat16* __restrict__ out, int width)
{
    const int row = blockIdx.x;
    const float* r = in + (size_t)row * width;
    float ss = 0.f;
    for (int i = threadIdx.x; i < width; i += 256) { float v = r[i]; ss += v * v; }
    ss = waveReduceSum(ss);
    __shared__ float red[4];
    if ((threadIdx.x & 63) == 0) red[threadIdx.x >> 6] = ss;
    __syncthreads();
    const float tot = red[0] + red[1] + red[2] + red[3];
    const float inv = 1.0f / sqrtf(tot / (float)width + EPSc);
    __hip_bfloat16* o = out + (size_t)row * width;
    for (int i = threadIdx.x; i < width; i += 256)
        o[i] = __float2bfloat16(gamma[i] * r[i] * inv);
}

// ---------------- fused per-head RMSNorm (D=128) + RoPE ----------------------
__global__ __launch_bounds__(128) void qknorm_rope_kernel(
    const __hip_bfloat16* in, const float* __restrict__ gamma,
    const float* __restrict__ sinp, const float* __restrict__ cosp,
    __hip_bfloat16* outB, float* outF, int heads)
{
    const int row = blockIdx.x;            // (b*T + t)*heads + h
    const int bt  = row / heads;           // b*T + t
    const int d   = threadIdx.x;           // 0..127
    const float v = __bfloat162float(in[(size_t)row * Dc + d]);
    float ss = waveReduceSum(v * v);
    __shared__ float red[2];
    __shared__ float nrm[Dc];
    if ((d & 63) == 0) red[d >> 6] = ss;
    __syncthreads();
    const float rms = sqrtf((red[0] + red[1]) * (1.0f / (float)Dc) + EPSc);
    const float xn = __bfloat162float(__float2bfloat16(gamma[d] * v / rms));
    nrm[d] = xn;
    __syncthreads();
    float res;
    if (d < 64) {
        const float s = sinp[(size_t)bt * 64 + d];
        const float c = cosp[(size_t)bt * 64 + d];
        res = nrm[d] * c - nrm[d + 64] * s;
    } else {
        const float s = sinp[(size_t)bt * 64 + (d - 64)];
        const float c = cosp[(size_t)bt * 64 + (d - 64)];
        res = nrm[d] * c + nrm[d - 64] * s;
    }
    outB[(size_t)row * Dc + d] = __float2bfloat16(res);
    if (outF) outF[(size_t)row * Dc + d] = res;   // un-rounded f32 (ref k dtype)
}

// ---------------- weight convert+transpose: W f32[K][N] -> Wt bf16[N][K] -----
__global__ __launch_bounds__(256) void convert_transpose_kernel(
    const float* __restrict__ W, __hip_bfloat16* __restrict__ Wt, int K, int N)
{
    __shared__ float tile[32][33];
    const int tx = threadIdx.x & 31;
    const int ty = threadIdx.x >> 5;       // 0..7
    const int n0 = blockIdx.x * 32;
    const int k0 = blockIdx.y * 32;
    for (int r = 0; r < 4; ++r) {
        const int k = ty + r * 8;
        tile[k][tx] = W[(size_t)(k0 + k) * N + n0 + tx];
    }
    __syncthreads();
    for (int r = 0; r < 4; ++r) {
        const int n = ty + r * 8;
        Wt[(size_t)(n0 + n) * K + k0 + tx] = __float2bfloat16(tile[tx][n]);
    }
}

// ============================================================================
// 256x256 8-phase GEMM. C[M,N] = A[M,K](bf16) @ Bt[N,K]^T (bf16).
// 512 threads = 8 waves (2 wm x 4 wn); per-wave 128x64 out; BK=64, 2 tiles/iter.
// LDS 128KB: As[2][256][64] | Bs[2][256][64], chunk-XOR swizzled.
// MODE: 0 bf16 out; 1 f32 resid+bf16(acc); 3 silu-mul; 4 dual.
// ============================================================================

__device__ __forceinline__ void stage_unitA256(
    const __hip_bfloat16* __restrict__ Ag, __hip_bfloat16* bufBase,
    int m0, int lda, int kk0, int h, int tid)
{
#pragma unroll
    for (int p = 0; p < 2; ++p) {
        const int ci = p * 512 + tid;          // 0..1023 chunks of 16B
        const int rl = ci >> 3;                // local row 0..127
        const int cc = ci & 7;                 // dest chunk (linear)
        const int grow = m0 + ((rl >> 6) * 128) + h * 64 + (rl & 63);
        const int scc = cc ^ (rl & 7);         // pre-swizzled source chunk
        load_lds_16(Ag + (size_t)grow * lda + kk0 + scc * 8,
                    bufBase + h * 8192 + ci * 8);
    }
}

__device__ __forceinline__ void stage_unitB256(
    const __hip_bfloat16* __restrict__ Bg, __hip_bfloat16* bufBase,
    int n0, int ldt, int kk0, int h, int tid)
{
#pragma unroll
    for (int p = 0; p < 2; ++p) {
        const int ci = p * 512 + tid;
        const int rl = ci >> 3;
        const int cc = ci & 7;
        const int grow = n0 + h * 128 + rl;
        const int scc = cc ^ (rl & 7);
        load_lds_16(Bg + (size_t)grow * ldt + kk0 + scc * 8,
                    bufBase + h * 8192 + ci * 8);
    }
}

__device__ __forceinline__ bf16x8 read_frag256(const __hip_bfloat16* buf,
                                               int r, int w)
{
    const int cc = w ^ (r & 7);                // swizzled read
    return *reinterpret_cast<const bf16x8*>(buf + r * 64 + cc * 8);
}

template <int MODE>
__global__ __launch_bounds__(512, 2) void gemm256_kernel(
    const __hip_bfloat16* __restrict__ A, const __hip_bfloat16* __restrict__ Bt,
    __hip_bfloat16* outB, float* outF, const float* resid,
    const __hip_bfloat16* gmul, int M, int N, int K, int lda, int ldt, int ldc)
{
    __shared__ __hip_bfloat16 smem[65536];     // 128 KB
    __hip_bfloat16* Ab0 = smem;
    __hip_bfloat16* Ab1 = smem + 16384;
    __hip_bfloat16* Bb0 = smem + 32768;
    __hip_bfloat16* Bb1 = smem + 49152;

    const int tid  = threadIdx.x;
    const int lane = tid & 63;
    const int wave = tid >> 6;
    const int l15  = lane & 15;
    const int quad = lane >> 4;
    const int wm   = wave >> 2;                // 0..1
    const int wn   = wave & 3;                 // 0..3
    const int m0   = blockIdx.y * 256;
    const int n0   = blockIdx.x * 256;
    const int NTt  = K >> 6;                   // 64-wide K tiles (even)

    f32x4 acc[8][4];
    const f32x4 zero = {0.f, 0.f, 0.f, 0.f};
#pragma unroll
    for (int i = 0; i < 8; ++i)
#pragma unroll
        for (int j = 0; j < 4; ++j) acc[i][j] = zero;

    // ---- prologue: tile0 fully, tile1 except A-unit1 (staged at Ph1) --------
    stage_unitA256(A, Ab0, m0, lda, 0, 0, tid);
    stage_unitA256(A, Ab0, m0, lda, 0, 1, tid);
    stage_unitB256(Bt, Bb0, n0, ldt, 0, 0, tid);
    stage_unitB256(Bt, Bb0, n0, ldt, 0, 1, tid);
    if (NTt > 1) {
        stage_unitA256(A, Ab1, m0, lda, 64, 0, tid);
        stage_unitB256(Bt, Bb1, n0, ldt, 64, 0, tid);
        stage_unitB256(Bt, Bb1, n0, ldt, 64, 1, tid);
    }
    asm volatile("s_waitcnt vmcnt(0)" ::: "memory");
    asm volatile("s_barrier" ::: "memory");

    bf16x8 bfr[4][2];
    bf16x8 af[4];

#define GB_READ_B(BB)                                                         \
    _Pragma("unroll")                                                         \
    for (int nt = 0; nt < 4; ++nt) {                                          \
        bfr[nt][0] = read_frag256(BB, wn * 64 + nt * 16 + l15, quad);         \
        bfr[nt][1] = read_frag256(BB, wn * 64 + nt * 16 + l15, 4 + quad);     \
    }
#define GB_READ_A(AB, MG, KS)                                                 \
    _Pragma("unroll")                                                         \
    for (int mq = 0; mq < 4; ++mq)                                            \
        af[mq] = read_frag256(AB, (MG)*128 + wm * 64 + mq * 16 + l15,         \
                              (KS)*4 + quad);
#define GB_MFMA(MG, KS)                                                       \
    __builtin_amdgcn_s_setprio(1);                                            \
    _Pragma("unroll")                                                         \
    for (int nt = 0; nt < 4; ++nt)                                            \
    _Pragma("unroll")                                                         \
    for (int mq = 0; mq < 4; ++mq)                                            \
        acc[(MG)*4 + mq][nt] = __builtin_amdgcn_mfma_f32_16x16x32_bf16(       \
            af[mq], bfr[nt][KS], acc[(MG)*4 + mq][nt], 0, 0, 0);              \
    __builtin_amdgcn_s_setprio(0);
#define SBAR256 asm volatile("s_barrier" ::: "memory")
#define VMC6    asm volatile("s_waitcnt vmcnt(6)" ::: "memory")

    const int nIter = NTt >> 1;
    for (int it = 0; it < nIter; ++it) {
        const int t1 = 2 * it + 1, t2 = 2 * it + 2, t3 = 2 * it + 3;
        // Ph1: compute t0 mg0 ks0; stage A1(t1) -> buf1.u1
        GB_READ_B(Bb0); GB_READ_A(Ab0, 0, 0);
        stage_unitA256(A, Ab1, m0, lda, t1 * 64, 1, tid);
        SBAR256; GB_MFMA(0, 0); SBAR256;
        // Ph2: t0 mg0 ks1; stage B0(t2)
        GB_READ_A(Ab0, 0, 1);
        if (t2 < NTt) stage_unitB256(Bt, Bb0, n0, ldt, t2 * 64, 0, tid);
        SBAR256; GB_MFMA(0, 1); SBAR256;
        // Ph3: t0 mg1 ks0; stage B1(t2)
        GB_READ_A(Ab0, 1, 0);
        if (t2 < NTt) stage_unitB256(Bt, Bb0, n0, ldt, t2 * 64, 1, tid);
        SBAR256; GB_MFMA(1, 0); SBAR256;
        // Ph4: t0 mg1 ks1; stage A0(t2); GATE vmcnt(6)
        GB_READ_A(Ab0, 1, 1);
        if (t2 < NTt) stage_unitA256(A, Ab0, m0, lda, t2 * 64, 0, tid);
        SBAR256; GB_MFMA(1, 1); VMC6; SBAR256;
        // Ph5: t1 mg0 ks0; stage A1(t2)
        GB_READ_B(Bb1); GB_READ_A(Ab1, 0, 0);
        if (t2 < NTt) stage_unitA256(A, Ab0, m0, lda, t2 * 64, 1, tid);
        SBAR256; GB_MFMA(0, 0); SBAR256;
        // Ph6: t1 mg0 ks1; stage B0(t3)
        GB_READ_A(Ab1, 0, 1);
        if (t3 < NTt) stage_unitB256(Bt, Bb1, n0, ldt, t3 * 64, 0, tid);
        SBAR256; GB_MFMA(0, 1); SBAR256;
        // Ph7: t1 mg1 ks0; stage B1(t3)
        GB_READ_A(Ab1, 1, 0);
        if (t3 < NTt) stage_unitB256(Bt, Bb1, n0, ldt, t3 * 64, 1, tid);
        SBAR256; GB_MFMA(1, 0); SBAR256;
        // Ph8: t1 mg1 ks1; stage A0(t3); GATE vmcnt(6)
        GB_READ_A(Ab1, 1, 1);
        if (t3 < NTt) stage_unitA256(A, Ab1, m0, lda, t3 * 64, 0, tid);
        SBAR256; GB_MFMA(1, 1); VMC6; SBAR256;
    }

#undef GB_READ_B
#undef GB_READ_A
#undef GB_MFMA
#undef SBAR256
#undef VMC6

    // ---- epilogue -----------------------------------------------------------
#pragma unroll
    for (int m = 0; m < 8; ++m) {
#pragma unroll
        for (int nt = 0; nt < 4; ++nt) {
            const f32x4 a  = acc[m][nt];
            const int col  = n0 + wn * 64 + nt * 16 + l15;
            const int rowb = m0 + wm * 128 + (m >> 2) * 64 + (m & 3) * 16 + quad * 4;
#pragma unroll
            for (int r = 0; r < 4; ++r) {
                const size_t idx = (size_t)(rowb + r) * ldc + col;
                const float val = a[r];
                if constexpr (MODE == 0) {
                    outB[idx] = __float2bfloat16(val);
                } else if constexpr (MODE == 1) {
                    outF[idx] = resid[idx] +
                                __bfloat162float(__float2bfloat16(val));
                } else if constexpr (MODE == 3) {
                    const float g = __bfloat162float(gmul[idx]);
                    const float sil = __bfloat162float(
                        __float2bfloat16(g / (1.f + __expf(-g))));
                    const float u = __bfloat162float(__float2bfloat16(val));
                    outB[idx] = __float2bfloat16(sil * u);
                } else { // MODE 4
                    const __hip_bfloat16 b = __float2bfloat16(val);
                    outB[idx] = b;
                    outF[idx] = __bfloat162float(b);
                }
            }
        }
    }
}

// ---------------- 128x128 bf16 GEMM (kept for N=1024 + small shapes) ---------
template <int MODE>
__global__ __launch_bounds__(256) void gemm_bt_kernel(
    const __hip_bfloat16* __restrict__ A, const __hip_bfloat16* __restrict__ Bt,
    __hip_bfloat16* outB, float* outF, const float* resid,
    const __hip_bfloat16* gmul, int M, int N, int K, int lda, int ldt)
{
    __shared__ __hip_bfloat16 As[128 * 32];
    __shared__ __hip_bfloat16 Bs[128 * 32];

    const int tid  = threadIdx.x;
    const int lane = tid & 63;
    const int wave = tid >> 6;
    const int l15  = lane & 15;
    const int quad = lane >> 4;
    const int q8   = quad * 8;
    const int wm   = wave >> 1;
    const int wn   = wave & 1;
    const int m0   = blockIdx.y * 128;
    const int n0   = blockIdx.x * 128;

    const int c0 = tid, c1 = tid + 256;
    const int r0 = c0 >> 2, o0 = (c0 & 3) * 8;
    const int r1 = c1 >> 2, o1 = (c1 & 3) * 8;
    const __hip_bfloat16* gA0 = A + (size_t)(m0 + r0) * lda + o0;
    const __hip_bfloat16* gA1 = A + (size_t)(m0 + r1) * lda + o1;
    const __hip_bfloat16* gB0 = Bt + (size_t)(n0 + r0) * ldt + o0;
    const __hip_bfloat16* gB1 = Bt + (size_t)(n0 + r1) * ldt + o1;

    f32x4 acc[4][4];
    const f32x4 zero = {0.f, 0.f, 0.f, 0.f};
#pragma unroll
    for (int i = 0; i < 4; ++i)
#pragma unroll
        for (int j = 0; j < 4; ++j) acc[i][j] = zero;

    for (int k0 = 0; k0 < K; k0 += 32) {
        __syncthreads();
        load_lds_16(gA0 + k0, As + c0 * 8);
        load_lds_16(gA1 + k0, As + c1 * 8);
        load_lds_16(gB0 + k0, Bs + c0 * 8);
        load_lds_16(gB1 + k0, Bs + c1 * 8);
        __syncthreads();

        bf16x8 af[4], bfv[4];
#pragma unroll
        for (int mt = 0; mt < 4; ++mt)
            af[mt] = *reinterpret_cast<const bf16x8*>(
                As + (wm * 64 + mt * 16 + l15) * 32 + q8);
#pragma unroll
        for (int nt = 0; nt < 4; ++nt)
            bfv[nt] = *reinterpret_cast<const bf16x8*>(
                Bs + (wn * 64 + nt * 16 + l15) * 32 + q8);
#pragma unroll
        for (int mt = 0; mt < 4; ++mt)
#pragma unroll
            for (int nt = 0; nt < 4; ++nt)
                acc[mt][nt] = __builtin_amdgcn_mfma_f32_16x16x32_bf16(
                    af[mt], bfv[nt], acc[mt][nt], 0, 0, 0);
    }

#pragma unroll
    for (int mt = 0; mt < 4; ++mt) {
#pragma unroll
        for (int nt = 0; nt < 4; ++nt) {
            const f32x4 a  = acc[mt][nt];
            const int col  = n0 + wn * 64 + nt * 16 + l15;
            const int rowb = m0 + wm * 64 + mt * 16 + quad * 4;
#pragma unroll
            for (int r = 0; r < 4; ++r) {
                const size_t idx = (size_t)(rowb + r) * N + col;
                const float val = a[r];
                if constexpr (MODE == 0) {
                    outB[idx] = __float2bfloat16(val);
                } else if constexpr (MODE == 1) {
                    outF[idx] = resid[idx] +
                                __bfloat162float(__float2bfloat16(val));
                } else if constexpr (MODE == 3) {
                    const float g = __bfloat162float(gmul[idx]);
                    const float sil = __bfloat162float(
                        __float2bfloat16(g / (1.f + __expf(-g))));
                    const float u = __bfloat162float(__float2bfloat16(val));
                    outB[idx] = __float2bfloat16(sil * u);
                } else {
                    const __hip_bfloat16 b = __float2bfloat16(val);
                    outB[idx] = b;
                    outF[idx] = __bfloat162float(b);
                }
            }
        }
    }
}

// ---------------- slow-path GEMM (f32 weights) — ws fallback -----------------
template <int MODE>
__global__ __launch_bounds__(256) void gemm_kernel(
    const __hip_bfloat16* __restrict__ A, const float* __restrict__ Bw,
    __hip_bfloat16* outB, float* outF, const float* resid,
    const __hip_bfloat16* gmul, int M, int N, int K, int ldb)
{
    __shared__ __hip_bfloat16 As[128][32];
    __shared__ __hip_bfloat16 Bs[128][40];

    const int tid  = threadIdx.x;
    const int lane = tid & 63;
    const int wave = tid >> 6;
    const int l15  = lane & 15;
    const int quad = lane >> 4;
    const int q8   = quad * 8;
    const int wm   = wave >> 1;
    const int wn   = wave & 1;
    const int m0   = blockIdx.y * 128;
    const int n0   = blockIdx.x * 128;

    f32x4 acc[4][4];
    const f32x4 zero = {0.f, 0.f, 0.f, 0.f};
#pragma unroll
    for (int i = 0; i < 4; ++i)
#pragma unroll
        for (int j = 0; j < 4; ++j) acc[i][j] = zero;

    const int nK = K >> 5;
    for (int kt = 0; kt < nK; ++kt) {
        const int k0 = kt << 5;
        __syncthreads();
#pragma unroll
        for (int vv = 0; vv < 2; ++vv) {
            const int vi  = vv * 256 + tid;
            const int row = vi >> 2;
            const int col = (vi & 3) * 8;
            *(short8*)(&As[row][col]) =
                *(const short8*)(A + (size_t)(m0 + row) * K + k0 + col);
        }
        {
            const int n  = tid & 127;
            const int kk = tid >> 7;
            const float* bp = Bw + (size_t)k0 * ldb + n0 + n;
#pragma unroll
            for (int p = 0; p < 16; ++p) {
                const int k = p * 2 + kk;
                Bs[n][k] = __float2bfloat16(bp[(size_t)k * ldb]);
            }
        }
        __syncthreads();
        bf16x8 af[4], bfv[4];
#pragma unroll
        for (int mt = 0; mt < 4; ++mt)
            af[mt] = *reinterpret_cast<const bf16x8*>(&As[wm * 64 + mt * 16 + l15][q8]);
#pragma unroll
        for (int nt = 0; nt < 4; ++nt)
            bfv[nt] = *reinterpret_cast<const bf16x8*>(&Bs[wn * 64 + nt * 16 + l15][q8]);
#pragma unroll
        for (int mt = 0; mt < 4; ++mt)
#pragma unroll
            for (int nt = 0; nt < 4; ++nt)
                acc[mt][nt] = __builtin_amdgcn_mfma_f32_16x16x32_bf16(
                    af[mt], bfv[nt], acc[mt][nt], 0, 0, 0);
    }

#pragma unroll
    for (int mt = 0; mt < 4; ++mt) {
#pragma unroll
        for (int nt = 0; nt < 4; ++nt) {
            const f32x4 a  = acc[mt][nt];
            const int col  = n0 + wn * 64 + nt * 16 + l15;
            const int rowb = m0 + wm * 64 + mt * 16 + quad * 4;
#pragma unroll
            for (int r = 0; r < 4; ++r) {
                const size_t idx = (size_t)(rowb + r) * N + col;
                const float val = a[r];
                if constexpr (MODE == 0) {
                    outB[idx] = __float2bfloat16(val);
                } else if constexpr (MODE == 1) {
                    outF[idx] = resid[idx] +
                                __bfloat162float(__float2bfloat16(val));
                } else if constexpr (MODE == 3) {
                    const float g = __bfloat162float(gmul[idx]);
                    const float sil = __bfloat162float(
                        __float2bfloat16(g / (1.f + __expf(-g))));
                    const float u = __bfloat162float(__float2bfloat16(val));
                    outB[idx] = __float2bfloat16(sil * u);
                } else {
                    const __hip_bfloat16 b = __float2bfloat16(val);
                    outB[idx] = b;
                    outF[idx] = __bfloat162float(b);
                }
            }
        }
    }
}

// ---------------- MFMA flash attention (unchanged this round) ----------------
__global__ __launch_bounds__(256) void flash_attn_kernel(
    const __hip_bfloat16* q, const __hip_bfloat16* __restrict__ k,
    const __hip_bfloat16* __restrict__ v, const int* __restrict__ mask,
    __hip_bfloat16* out)
{
    __shared__ unsigned short Ks[64][136];
    __shared__ unsigned short Vs[128][72];
    __shared__ unsigned short Ps[4][16][72];
    __shared__ int msk[64];

    const int tid  = threadIdx.x;
    const int lane = tid & 63;
    const int wave = tid >> 6;
    const int l15  = lane & 15;
    const int quad = lane >> 4;
    const int q0   = blockIdx.x * 64;
    const int bh   = blockIdx.y;
    const int b    = bh >> 4;
    const int h    = bh & 15;
    const int kh   = h >> 1;

    const float scale = 0.08838834764831845f;

    bf16x8 qf[4];
    {
        const __hip_bfloat16* qp =
            q + (((size_t)(b * Tc + q0 + wave * 16 + l15)) * QHc + h) * Dc;
#pragma unroll
        for (int kk = 0; kk < 4; ++kk)
            qf[kk] = *(const bf16x8*)(qp + kk * 32 + quad * 8);
    }

    float mrow[4] = {MASKVAL, MASKVAL, MASKVAL, MASKVAL};
    float lrow[4] = {0.f, 0.f, 0.f, 0.f};
    f32x4 oacc[8];
#pragma unroll
    for (int i = 0; i < 8; ++i) oacc[i] = (f32x4){0.f, 0.f, 0.f, 0.f};

    const int ktmax = q0 >> 6;
    for (int kt = 0; kt <= ktmax; ++kt) {
        const int kvbase = kt * 64;
        __syncthreads();
#pragma unroll
        for (int i = 0; i < 4; ++i) {
            const int c  = i * 256 + tid;
            const int kv = c >> 4;
            const int d0 = (c & 15) * 8;
            *(bf16x8*)(&Ks[kv][d0]) = *(const bf16x8*)(
                k + (((size_t)(b * Tc + kvbase + kv)) * KHc + kh) * Dc + d0);
        }
        {
            const int kv = tid & 63;
            const int g0 = (tid >> 6) * 4;
            for (int g = g0; g < g0 + 4; ++g) {
                const int d0 = g * 8;
                const short8 tmp = *(const short8*)(
                    v + (((size_t)(b * Tc + kvbase + kv)) * KHc + kh) * Dc + d0);
#pragma unroll
                for (int j = 0; j < 8; ++j)
                    Vs[d0 + j][kv] = (unsigned short)tmp[j];
            }
        }
        if (tid < 64) msk[tid] = mask[b * Tc + kvbase + tid];
        __syncthreads();

        f32x4 sacc[4];
#pragma unroll
        for (int nt = 0; nt < 4; ++nt) sacc[nt] = (f32x4){0.f, 0.f, 0.f, 0.f};
#pragma unroll
        for (int nt = 0; nt < 4; ++nt)
#pragma unroll
            for (int kk = 0; kk < 4; ++kk) {
                const bf16x8 kf = *(const bf16x8*)(&Ks[nt * 16 + l15][kk * 32 + quad * 8]);
                sacc[nt] = __builtin_amdgcn_mfma_f32_16x16x32_bf16(
                    qf[kk], kf, sacc[nt], 0, 0, 0);
            }

        float tmax[4] = {MASKVAL, MASKVAL, MASKVAL, MASKVAL};
#pragma unroll
        for (int nt = 0; nt < 4; ++nt) {
            const int kvpos  = kvbase + nt * 16 + l15;
            const bool kvld  = (msk[nt * 16 + l15] != 0);
#pragma unroll
            for (int r = 0; r < 4; ++r) {
                const int qr = q0 + wave * 16 + quad * 4 + r;
                float s = sacc[nt][r] * scale;
                s = (kvld && kvpos <= qr) ? s : MASKVAL;
                sacc[nt][r] = s;
                tmax[r] = fmaxf(tmax[r], s);
            }
        }
#pragma unroll
        for (int r = 0; r < 4; ++r)
            for (int off = 1; off < 16; off <<= 1)
                tmax[r] = fmaxf(tmax[r], __shfl_xor(tmax[r], off, 64));

        float alpha[4];
#pragma unroll
        for (int r = 0; r < 4; ++r) {
            const float mnew = fmaxf(mrow[r], tmax[r]);
            alpha[r] = __expf(mrow[r] - mnew);
            mrow[r]  = mnew;
        }
        float tsum[4] = {0.f, 0.f, 0.f, 0.f};
#pragma unroll
        for (int nt = 0; nt < 4; ++nt)
#pragma unroll
            for (int r = 0; r < 4; ++r) {
                const float p = __expf(sacc[nt][r] - mrow[r]);
                sacc[nt][r] = p;
                tsum[r] += p;
            }
#pragma unroll
        for (int r = 0; r < 4; ++r)
            for (int off = 1; off < 16; off <<= 1)
                tsum[r] += __shfl_xor(tsum[r], off, 64);
#pragma unroll
        for (int r = 0; r < 4; ++r)
            lrow[r] = lrow[r] * alpha[r] + tsum[r];

#pragma unroll
        for (int nt = 0; nt < 4; ++nt)
#pragma unroll
            for (int r = 0; r < 4; ++r) {
                const __hip_bfloat16 pb = __float2bfloat16(sacc[nt][r]);
                Ps[wave][quad * 4 + r][nt * 16 + l15] =
                    *(const unsigned short*)&pb;
            }
        __syncthreads();

#pragma unroll
        for (int ntd = 0; ntd < 8; ++ntd)
#pragma unroll
            for (int r = 0; r < 4; ++r) oacc[ntd][r] *= alpha[r];
        bf16x8 pa[2];
#pragma unroll
        for (int kk2 = 0; kk2 < 2; ++kk2)
            pa[kk2] = *(const bf16x8*)(&Ps[wave][l15][kk2 * 32 + quad * 8]);
#pragma unroll
        for (int ntd = 0; ntd < 8; ++ntd)
#pragma unroll
            for (int kk2 = 0; kk2 < 2; ++kk2) {
                const bf16x8 vf = *(const bf16x8*)(
                    &Vs[ntd * 16 + l15][kk2 * 32 + quad * 8]);
                oacc[ntd] = __builtin_amdgcn_mfma_f32_16x16x32_bf16(
                    pa[kk2], vf, oacc[ntd], 0, 0, 0);
            }
    }

#pragma unroll
    for (int ntd = 0; ntd < 8; ++ntd)
#pragma unroll
        for (int r = 0; r < 4; ++r) {
            const float li = lrow[r];
            const float o  = (li > 0.f) ? oacc[ntd][r] / li : 0.f;
            const int qr   = q0 + wave * 16 + quad * 4 + r;
            out[(((size_t)(b * Tc + qr)) * QHc + h) * Dc + ntd * 16 + l15] =
                __float2bfloat16(o);
        }
}

// ---------------------------------------------------------------------------
extern "C" void kernel_launch(void* const* d_in, const int* in_sizes, int n_in,
                              void* d_out, int out_size, void* d_ws, size_t ws_size,
                              hipStream_t stream) {
    const float* x          = (const float*)d_in[0];
    const float* sinp       = (const float*)d_in[1];
    const float* cosp       = (const float*)d_in[2];
    const int*   token_mask = (const int*)d_in[3];
    const float* pre_gamma  = (const float*)d_in[5];
    const float* wq         = (const float*)d_in[6];
    const float* wk         = (const float*)d_in[7];
    const float* wv         = (const float*)d_in[8];
    const float* q_gamma    = (const float*)d_in[9];
    const float* k_gamma    = (const float*)d_in[10];
    const float* wo         = (const float*)d_in[11];
    const float* post_gamma = (const float*)d_in[12];
    const float* wg         = (const float*)d_in[13];
    const float* wu         = (const float*)d_in[14];
    const float* wd         = (const float*)d_in[15];

    // d_out sections, ALL FLOAT32: x | k | v
    float* outx = (float*)d_out;
    float* outk = outx + (size_t)Bc * Tc * Hc;
    float* outv = outk + (size_t)Bc * Tc * KHc * Dc;

    const bool fast = (ws_size >= 176160768ull);

    if (fast) {
        // ---- fast path: bf16 transposed weights in ws -----------------------
        char* w = (char*)d_ws;
        __hip_bfloat16* wq_t  = (__hip_bfloat16*)(w);               //  8.39 MB
        __hip_bfloat16* wk_t  = (__hip_bfloat16*)(w + 8388608);     //  4.19 MB
        __hip_bfloat16* wv_t  = (__hip_bfloat16*)(w + 12582912);    //  4.19 MB
        __hip_bfloat16* wo_t  = (__hip_bfloat16*)(w + 16777216);    //  8.39 MB
        __hip_bfloat16* wg_t  = (__hip_bfloat16*)(w + 25165824);    // 33.55 MB
        __hip_bfloat16* wu_t  = (__hip_bfloat16*)(w + 58720256);    // 33.55 MB
        __hip_bfloat16* wd_t  = (__hip_bfloat16*)(w + 92274688);    // 33.55 MB
        __hip_bfloat16* xnorm = (__hip_bfloat16*)(w + 125829120);   // 16.78 MB
        __hip_bfloat16* qbuf  = (__hip_bfloat16*)(w + 142606336);   // 16.78 MB
        __hip_bfloat16* kbuf  = (__hip_bfloat16*)(w + 159383552);   //  8.39 MB
        __hip_bfloat16* vbuf  = (__hip_bfloat16*)(w + 167772160);   //  8.39 MB
        // Gbig = qbuf|kbuf|vbuf contiguous 33.55 MB, free after attention+wo
        __hip_bfloat16* Gbig  = qbuf;

        // 0. convert+transpose all weights (f32 [K][N] -> bf16 [N][K])
        convert_transpose_kernel<<<dim3(Hc/32, Hc/32), 256, 0, stream>>>(wq, wq_t, Hc, Hc);
        convert_transpose_kernel<<<dim3((KHc*Dc)/32, Hc/32), 256, 0, stream>>>(wk, wk_t, Hc, KHc*Dc);
        convert_transpose_kernel<<<dim3((KHc*Dc)/32, Hc/32), 256, 0, stream>>>(wv, wv_t, Hc, KHc*Dc);
        convert_transpose_kernel<<<dim3(Hc/32, Hc/32), 256, 0, stream>>>(wo, wo_t, Hc, Hc);
        convert_transpose_kernel<<<dim3(Fc/32, Hc/32), 256, 0, stream>>>(wg, wg_t, Hc, Fc);
        convert_transpose_kernel<<<dim3(Fc/32, Hc/32), 256, 0, stream>>>(wu, wu_t, Hc, Fc);
        convert_transpose_kernel<<<dim3(Hc/32, Fc/32), 256, 0, stream>>>(wd, wd_t, Fc, Hc);

        // 1. pre-RMSNorm
        rmsnorm_f32_kernel<<<Mc, 256, 0, stream>>>(x, pre_gamma, xnorm, Hc);

        // 2-4. QKV projections (wq on 256^2 8-phase; wk/wv N=1024 on 128^2)
        gemm256_kernel<0><<<dim3(Hc/256, Mc/256), 512, 0, stream>>>(
            xnorm, wq_t, qbuf, nullptr, nullptr, nullptr, Mc, Hc, Hc, Hc, Hc, Hc);
        gemm_bt_kernel<0><<<dim3((KHc*Dc)/128, Mc/128), 256, 0, stream>>>(
            xnorm, wk_t, kbuf, nullptr, nullptr, nullptr, Mc, KHc*Dc, Hc, Hc, Hc);
        gemm_bt_kernel<4><<<dim3((KHc*Dc)/128, Mc/128), 256, 0, stream>>>(
            xnorm, wv_t, vbuf, outv, nullptr, nullptr, Mc, KHc*Dc, Hc, Hc, Hc);

        // 5-6. per-head RMSNorm + RoPE
        qknorm_rope_kernel<<<Mc*QHc, 128, 0, stream>>>(
            qbuf, q_gamma, sinp, cosp, qbuf, nullptr, QHc);
        qknorm_rope_kernel<<<Mc*KHc, 128, 0, stream>>>(
            kbuf, k_gamma, sinp, cosp, kbuf, outk, KHc);

        // 7. MFMA flash attention
        flash_attn_kernel<<<dim3(Tc/64, Bc*QHc), 256, 0, stream>>>(
            qbuf, kbuf, vbuf, token_mask, qbuf);

        // 8. wo projection + residual -> outx
        gemm256_kernel<1><<<dim3(Hc/256, Mc/256), 512, 0, stream>>>(
            qbuf, wo_t, nullptr, outx, x, nullptr, Mc, Hc, Hc, Hc, Hc, Hc);

        // 9. post-RMSNorm
        rmsnorm_f32_kernel<<<Mc, 256, 0, stream>>>(outx, post_gamma, xnorm, Hc);

        // 10. MLP in 2 half-F passes of 4096 (wg/wu at full-GPU 256 WGs)
        for (int hh = 0; hh < 2; ++hh) {
            const __hip_bfloat16* wg_h = wg_t + (size_t)hh * 4096 * Hc;
            const __hip_bfloat16* wu_h = wu_t + (size_t)hh * 4096 * Hc;
            const __hip_bfloat16* wd_h = wd_t + (size_t)hh * 4096;   // k-cols
            gemm256_kernel<0><<<dim3(4096/256, Mc/256), 512, 0, stream>>>(
                xnorm, wg_h, Gbig, nullptr, nullptr, nullptr,
                Mc, 4096, Hc, Hc, Hc, 4096);
            gemm256_kernel<3><<<dim3(4096/256, Mc/256), 512, 0, stream>>>(
                xnorm, wu_h, Gbig, nullptr, nullptr, Gbig,
                Mc, 4096, Hc, Hc, Hc, 4096);
            gemm256_kernel<1><<<dim3(Hc/256, Mc/256), 512, 0, stream>>>(
                Gbig, wd_h, nullptr, outx, outx, nullptr,
                Mc, Hc, 4096, 4096, Fc, Hc);
        }
    } else {
        // ---- fallback: f32-weight path (48 MB ws) ---------------------------
        char* w = (char*)d_ws;
        __hip_bfloat16* xnorm = (__hip_bfloat16*)(w);
        __hip_bfloat16* qbuf  = (__hip_bfloat16*)(w + 16777216);
        __hip_bfloat16* kbuf  = (__hip_bfloat16*)(w + 33554432);
        __hip_bfloat16* vbuf  = (__hip_bfloat16*)(w + 41943040);
        __hip_bfloat16* Gtmp  = qbuf;

        rmsnorm_f32_kernel<<<Mc, 256, 0, stream>>>(x, pre_gamma, xnorm, Hc);
        gemm_kernel<0><<<dim3(Hc/128, Mc/128), 256, 0, stream>>>(
            xnorm, wq, qbuf, nullptr, nullptr, nullptr, Mc, Hc, Hc, Hc);
        gemm_kernel<0><<<dim3((KHc*Dc)/128, Mc/128), 256, 0, stream>>>(
            xnorm, wk, kbuf, nullptr, nullptr, nullptr, Mc, KHc*Dc, Hc, KHc*Dc);
        gemm_kernel<4><<<dim3((KHc*Dc)/128, Mc/128), 256, 0, stream>>>(
            xnorm, wv, vbuf, outv, nullptr, nullptr, Mc, KHc*Dc, Hc, KHc*Dc);
        qknorm_rope_kernel<<<Mc*QHc, 128, 0, stream>>>(
            qbuf, q_gamma, sinp, cosp, qbuf, nullptr, QHc);
        qknorm_rope_kernel<<<Mc*KHc, 128, 0, stream>>>(
            kbuf, k_gamma, sinp, cosp, kbuf, outk, KHc);
        flash_attn_kernel<<<dim3(Tc/64, Bc*QHc), 256, 0, stream>>>(
            qbuf, kbuf, vbuf, token_mask, qbuf);
        gemm_kernel<1><<<dim3(Hc/128, Mc/128), 256, 0, stream>>>(
            qbuf, wo, nullptr, outx, x, nullptr, Mc, Hc, Hc, Hc);
        rmsnorm_f32_kernel<<<Mc, 256, 0, stream>>>(outx, post_gamma, xnorm, Hc);
        for (int c = 0; c < 4; ++c) {
            const float* wg_c = wg + (size_t)c * FCHUNK;
            const float* wu_c = wu + (size_t)c * FCHUNK;
            const float* wd_c = wd + (size_t)c * FCHUNK * Hc;
            gemm_kernel<0><<<dim3(FCHUNK/128, Mc/128), 256, 0, stream>>>(
                xnorm, wg_c, Gtmp, nullptr, nullptr, nullptr, Mc, FCHUNK, Hc, Fc);
            gemm_kernel<3><<<dim3(FCHUNK/128, Mc/128), 256, 0, stream>>>(
                xnorm, wu_c, Gtmp, nullptr, nullptr, Gtmp, Mc, FCHUNK, Hc, Fc);
            gemm_kernel<1><<<dim3(Hc/128, Mc/128), 256, 0, stream>>>(
                Gtmp, wd_c, nullptr, outx, outx, nullptr, Mc, Hc, FCHUNK, Hc);
        }
    }
}

// Round 3
// 1165.164 us; speedup vs baseline: 5.1598x; 1.1855x over previous
//
#include <hip/hip_runtime.h>
#include <hip/hip_bf16.h>

// ---------------------------------------------------------------------------
// Transformer block on MI355X. B=2, T=2048, H=2048, QH=16, KH=8, D=128, F=8192
// Outputs concatenated in d_out as FLOAT32: x | k | v
// Round 7 -> 8:
//  * flash_attn: q-tile PAIRING (bx, 31-bx) -> uniform 33-iter blocks, grid
//    (16,32); T14 reg-prefetch of next K/V/mask tile (hides global latency
//    under compute); removed redundant post-Ps barrier; setprio around MFMA.
//  * fused QKV projection: wq_t|wk_t|wv_t contiguous [4096][2048] -> one
//    gemm256 N=4096 launch, MODE 5 epilogue splits q/k/v (+outv f32).
//  * wd projection: MODE 2 split-K (grid.z=2, K=2048 slices) with f32
//    unsafeAtomicAdd into outx -> full-GPU launches instead of 128-WG halves.
// gemm256 ledger unchanged (see round-7 comment block in git history).
// ---------------------------------------------------------------------------

#define Bc  2
#define Tc  2048
#define Hc  2048
#define QHc 16
#define KHc 8
#define Dc  128
#define Fc  8192
#define Mc  (Bc*Tc)          // 4096 rows
#define FCHUNK 2048          // fallback MLP F-chunk
#define EPSc 1e-6f
#define MASKVAL (-1e30f)

typedef __bf16  bf16x8 __attribute__((ext_vector_type(8)));
typedef short   short8 __attribute__((ext_vector_type(8)));
typedef float   f32x4  __attribute__((ext_vector_type(4)));

// ---------------- reductions -------------------------------------------------
__device__ __forceinline__ float waveReduceSum(float v) {
    for (int off = 32; off > 0; off >>= 1) v += __shfl_down(v, off, 64);
    return v;
}

// ---------------- async global->LDS 16B helper -------------------------------
__device__ __forceinline__ void load_lds_16(const __hip_bfloat16* g,
                                            __hip_bfloat16* l) {
    __builtin_amdgcn_global_load_lds(
        (const __attribute__((address_space(1))) void*)g,
        (__attribute__((address_space(3))) void*)l, 16, 0, 0);
}

// ---------------- RMSNorm over f32 rows -> bf16 ------------------------------
__global__ __launch_bounds__(256) void rmsnorm_f32_kernel(
    const float* __restrict__ in, const float* __restrict__ gamma,
    __hip_bfloat16* __restrict__ out, int width)
{
    const int row = blockIdx.x;
    const float* r = in + (size_t)row * width;
    float ss = 0.f;
    for (int i = threadIdx.x; i < width; i += 256) { float v = r[i]; ss += v * v; }
    ss = waveReduceSum(ss);
    __shared__ float red[4];
    if ((threadIdx.x & 63) == 0) red[threadIdx.x >> 6] = ss;
    __syncthreads();
    const float tot = red[0] + red[1] + red[2] + red[3];
    const float inv = 1.0f / sqrtf(tot / (float)width + EPSc);
    __hip_bfloat16* o = out + (size_t)row * width;
    for (int i = threadIdx.x; i < width; i += 256)
        o[i] = __float2bfloat16(gamma[i] * r[i] * inv);
}

// ---------------- fused per-head RMSNorm (D=128) + RoPE ----------------------
__global__ __launch_bounds__(128) void qknorm_rope_kernel(
    const __hip_bfloat16* in, const float* __restrict__ gamma,
    const float* __restrict__ sinp, const float* __restrict__ cosp,
    __hip_bfloat16* outB, float* outF, int heads)
{
    const int row = blockIdx.x;            // (b*T + t)*heads + h
    const int bt  = row / heads;           // b*T + t
    const int d   = threadIdx.x;           // 0..127
    const float v = __bfloat162float(in[(size_t)row * Dc + d]);
    float ss = waveReduceSum(v * v);
    __shared__ float red[2];
    __shared__ float nrm[Dc];
    if ((d & 63) == 0) red[d >> 6] = ss;
    __syncthreads();
    const float rms = sqrtf((red[0] + red[1]) * (1.0f / (float)Dc) + EPSc);
    const float xn = __bfloat162float(__float2bfloat16(gamma[d] * v / rms));
    nrm[d] = xn;
    __syncthreads();
    float res;
    if (d < 64) {
        const float s = sinp[(size_t)bt * 64 + d];
        const float c = cosp[(size_t)bt * 64 + d];
        res = nrm[d] * c - nrm[d + 64] * s;
    } else {
        const float s = sinp[(size_t)bt * 64 + (d - 64)];
        const float c = cosp[(size_t)bt * 64 + (d - 64)];
        res = nrm[d] * c + nrm[d - 64] * s;
    }
    outB[(size_t)row * Dc + d] = __float2bfloat16(res);
    if (outF) outF[(size_t)row * Dc + d] = res;   // un-rounded f32 (ref k dtype)
}

// ---------------- weight convert+transpose: W f32[K][N] -> Wt bf16[N][K] -----
__global__ __launch_bounds__(256) void convert_transpose_kernel(
    const float* __restrict__ W, __hip_bfloat16* __restrict__ Wt, int K, int N)
{
    __shared__ float tile[32][33];
    const int tx = threadIdx.x & 31;
    const int ty = threadIdx.x >> 5;       // 0..7
    const int n0 = blockIdx.x * 32;
    const int k0 = blockIdx.y * 32;
    for (int r = 0; r < 4; ++r) {
        const int k = ty + r * 8;
        tile[k][tx] = W[(size_t)(k0 + k) * N + n0 + tx];
    }
    __syncthreads();
    for (int r = 0; r < 4; ++r) {
        const int n = ty + r * 8;
        Wt[(size_t)(n0 + n) * K + k0 + tx] = __float2bfloat16(tile[tx][n]);
    }
}

// ============================================================================
// 256x256 8-phase GEMM. C[M,N] = A[M,K](bf16) @ Bt[N,K]^T (bf16).
// 512 threads = 8 waves (2 wm x 4 wn); per-wave 128x64 out; BK=64, 2 tiles/iter.
// LDS 128KB: As[2][256][64] | Bs[2][256][64], chunk-XOR swizzled.
// MODE: 0 bf16 out; 1 f32 resid+bf16(acc); 2 split-K f32 atomic into outF
//       (grid.z slices of depth K); 3 silu-mul; 4 dual; 5 fused-QKV split.
// ============================================================================

__device__ __forceinline__ void stage_unitA256(
    const __hip_bfloat16* __restrict__ Ag, __hip_bfloat16* bufBase,
    int m0, int lda, int kk0, int h, int tid)
{
#pragma unroll
    for (int p = 0; p < 2; ++p) {
        const int ci = p * 512 + tid;          // 0..1023 chunks of 16B
        const int rl = ci >> 3;                // local row 0..127
        const int cc = ci & 7;                 // dest chunk (linear)
        const int grow = m0 + ((rl >> 6) * 128) + h * 64 + (rl & 63);
        const int scc = cc ^ (rl & 7);         // pre-swizzled source chunk
        load_lds_16(Ag + (size_t)grow * lda + kk0 + scc * 8,
                    bufBase + h * 8192 + ci * 8);
    }
}

__device__ __forceinline__ void stage_unitB256(
    const __hip_bfloat16* __restrict__ Bg, __hip_bfloat16* bufBase,
    int n0, int ldt, int kk0, int h, int tid)
{
#pragma unroll
    for (int p = 0; p < 2; ++p) {
        const int ci = p * 512 + tid;
        const int rl = ci >> 3;
        const int cc = ci & 7;
        const int grow = n0 + h * 128 + rl;
        const int scc = cc ^ (rl & 7);
        load_lds_16(Bg + (size_t)grow * ldt + kk0 + scc * 8,
                    bufBase + h * 8192 + ci * 8);
    }
}

__device__ __forceinline__ bf16x8 read_frag256(const __hip_bfloat16* buf,
                                               int r, int w)
{
    const int cc = w ^ (r & 7);                // swizzled read
    return *reinterpret_cast<const bf16x8*>(buf + r * 64 + cc * 8);
}

template <int MODE>
__global__ __launch_bounds__(512, 2) void gemm256_kernel(
    const __hip_bfloat16* __restrict__ A, const __hip_bfloat16* __restrict__ Bt,
    __hip_bfloat16* outB, float* outF, const float* resid,
    const __hip_bfloat16* gmul, int M, int N, int K, int lda, int ldt, int ldc)
{
    __shared__ __hip_bfloat16 smem[65536];     // 128 KB
    __hip_bfloat16* Ab0 = smem;
    __hip_bfloat16* Ab1 = smem + 16384;
    __hip_bfloat16* Bb0 = smem + 32768;
    __hip_bfloat16* Bb1 = smem + 49152;

    if constexpr (MODE == 2) {                 // split-K slice along k
        A  += (size_t)blockIdx.z * K;
        Bt += (size_t)blockIdx.z * K;
    }

    const int tid  = threadIdx.x;
    const int lane = tid & 63;
    const int wave = tid >> 6;
    const int l15  = lane & 15;
    const int quad = lane >> 4;
    const int wm   = wave >> 2;                // 0..1
    const int wn   = wave & 3;                 // 0..3
    const int m0   = blockIdx.y * 256;
    const int n0   = blockIdx.x * 256;
    const int NTt  = K >> 6;                   // 64-wide K tiles (even)

    f32x4 acc[8][4];
    const f32x4 zero = {0.f, 0.f, 0.f, 0.f};
#pragma unroll
    for (int i = 0; i < 8; ++i)
#pragma unroll
        for (int j = 0; j < 4; ++j) acc[i][j] = zero;

    // ---- prologue: tile0 fully, tile1 except A-unit1 (staged at Ph1) --------
    stage_unitA256(A, Ab0, m0, lda, 0, 0, tid);
    stage_unitA256(A, Ab0, m0, lda, 0, 1, tid);
    stage_unitB256(Bt, Bb0, n0, ldt, 0, 0, tid);
    stage_unitB256(Bt, Bb0, n0, ldt, 0, 1, tid);
    if (NTt > 1) {
        stage_unitA256(A, Ab1, m0, lda, 64, 0, tid);
        stage_unitB256(Bt, Bb1, n0, ldt, 64, 0, tid);
        stage_unitB256(Bt, Bb1, n0, ldt, 64, 1, tid);
    }
    asm volatile("s_waitcnt vmcnt(0)" ::: "memory");
    asm volatile("s_barrier" ::: "memory");

    bf16x8 bfr[4][2];
    bf16x8 af[4];

#define GB_READ_B(BB)                                                         \
    _Pragma("unroll")                                                         \
    for (int nt = 0; nt < 4; ++nt) {                                          \
        bfr[nt][0] = read_frag256(BB, wn * 64 + nt * 16 + l15, quad);         \
        bfr[nt][1] = read_frag256(BB, wn * 64 + nt * 16 + l15, 4 + quad);     \
    }
#define GB_READ_A(AB, MG, KS)                                                 \
    _Pragma("unroll")                                                         \
    for (int mq = 0; mq < 4; ++mq)                                            \
        af[mq] = read_frag256(AB, (MG)*128 + wm * 64 + mq * 16 + l15,         \
                              (KS)*4 + quad);
#define GB_MFMA(MG, KS)                                                       \
    __builtin_amdgcn_s_setprio(1);                                            \
    _Pragma("unroll")                                                         \
    for (int nt = 0; nt < 4; ++nt)                                            \
    _Pragma("unroll")                                                         \
    for (int mq = 0; mq < 4; ++mq)                                            \
        acc[(MG)*4 + mq][nt] = __builtin_amdgcn_mfma_f32_16x16x32_bf16(       \
            af[mq], bfr[nt][KS], acc[(MG)*4 + mq][nt], 0, 0, 0);              \
    __builtin_amdgcn_s_setprio(0);
#define SBAR256 asm volatile("s_barrier" ::: "memory")
#define VMC6    asm volatile("s_waitcnt vmcnt(6)" ::: "memory")

    const int nIter = NTt >> 1;
    for (int it = 0; it < nIter; ++it) {
        const int t1 = 2 * it + 1, t2 = 2 * it + 2, t3 = 2 * it + 3;
        // Ph1: compute t0 mg0 ks0; stage A1(t1) -> buf1.u1
        GB_READ_B(Bb0); GB_READ_A(Ab0, 0, 0);
        stage_unitA256(A, Ab1, m0, lda, t1 * 64, 1, tid);
        SBAR256; GB_MFMA(0, 0); SBAR256;
        // Ph2: t0 mg0 ks1; stage B0(t2)
        GB_READ_A(Ab0, 0, 1);
        if (t2 < NTt) stage_unitB256(Bt, Bb0, n0, ldt, t2 * 64, 0, tid);
        SBAR256; GB_MFMA(0, 1); SBAR256;
        // Ph3: t0 mg1 ks0; stage B1(t2)
        GB_READ_A(Ab0, 1, 0);
        if (t2 < NTt) stage_unitB256(Bt, Bb0, n0, ldt, t2 * 64, 1, tid);
        SBAR256; GB_MFMA(1, 0); SBAR256;
        // Ph4: t0 mg1 ks1; stage A0(t2); GATE vmcnt(6)
        GB_READ_A(Ab0, 1, 1);
        if (t2 < NTt) stage_unitA256(A, Ab0, m0, lda, t2 * 64, 0, tid);
        SBAR256; GB_MFMA(1, 1); VMC6; SBAR256;
        // Ph5: t1 mg0 ks0; stage A1(t2)
        GB_READ_B(Bb1); GB_READ_A(Ab1, 0, 0);
        if (t2 < NTt) stage_unitA256(A, Ab0, m0, lda, t2 * 64, 1, tid);
        SBAR256; GB_MFMA(0, 0); SBAR256;
        // Ph6: t1 mg0 ks1; stage B0(t3)
        GB_READ_A(Ab1, 0, 1);
        if (t3 < NTt) stage_unitB256(Bt, Bb1, n0, ldt, t3 * 64, 0, tid);
        SBAR256; GB_MFMA(0, 1); SBAR256;
        // Ph7: t1 mg1 ks0; stage B1(t3)
        GB_READ_A(Ab1, 1, 0);
        if (t3 < NTt) stage_unitB256(Bt, Bb1, n0, ldt, t3 * 64, 1, tid);
        SBAR256; GB_MFMA(1, 0); SBAR256;
        // Ph8: t1 mg1 ks1; stage A0(t3); GATE vmcnt(6)
        GB_READ_A(Ab1, 1, 1);
        if (t3 < NTt) stage_unitA256(A, Ab1, m0, lda, t3 * 64, 0, tid);
        SBAR256; GB_MFMA(1, 1); VMC6; SBAR256;
    }

#undef GB_READ_B
#undef GB_READ_A
#undef GB_MFMA
#undef SBAR256
#undef VMC6

    // ---- epilogue -----------------------------------------------------------
#pragma unroll
    for (int m = 0; m < 8; ++m) {
#pragma unroll
        for (int nt = 0; nt < 4; ++nt) {
            const f32x4 a  = acc[m][nt];
            const int col  = n0 + wn * 64 + nt * 16 + l15;
            const int rowb = m0 + wm * 128 + (m >> 2) * 64 + (m & 3) * 16 + quad * 4;
#pragma unroll
            for (int r = 0; r < 4; ++r) {
                const size_t idx = (size_t)(rowb + r) * ldc + col;
                const float val = a[r];
                if constexpr (MODE == 0) {
                    outB[idx] = __float2bfloat16(val);
                } else if constexpr (MODE == 1) {
                    outF[idx] = resid[idx] +
                                __bfloat162float(__float2bfloat16(val));
                } else if constexpr (MODE == 2) {
                    unsafeAtomicAdd(&outF[idx], val);   // split-K accumulate
                } else if constexpr (MODE == 3) {
                    const float g = __bfloat162float(gmul[idx]);
                    const float sil = __bfloat162float(
                        __float2bfloat16(g / (1.f + __expf(-g))));
                    const float u = __bfloat162float(__float2bfloat16(val));
                    outB[idx] = __float2bfloat16(sil * u);
                } else if constexpr (MODE == 4) {
                    const __hip_bfloat16 b = __float2bfloat16(val);
                    outB[idx] = b;
                    outF[idx] = __bfloat162float(b);
                } else { // MODE 5: fused QKV. outB=qbuf (k,v contiguous after),
                         // outF=outv. Region is block-uniform (n0 mult of 256).
                    if (n0 < 2048) {
                        outB[(size_t)(rowb + r) * 2048 + col] =
                            __float2bfloat16(val);
                    } else if (n0 < 3072) {
                        outB[8388608 + (size_t)(rowb + r) * 1024 + (col - 2048)] =
                            __float2bfloat16(val);
                    } else {
                        const __hip_bfloat16 b = __float2bfloat16(val);
                        outB[12582912 + (size_t)(rowb + r) * 1024 + (col - 3072)] = b;
                        outF[(size_t)(rowb + r) * 1024 + (col - 3072)] =
                            __bfloat162float(b);
                    }
                }
            }
        }
    }
}

// ---------------- slow-path GEMM (f32 weights) — ws fallback -----------------
template <int MODE>
__global__ __launch_bounds__(256) void gemm_kernel(
    const __hip_bfloat16* __restrict__ A, const float* __restrict__ Bw,
    __hip_bfloat16* outB, float* outF, const float* resid,
    const __hip_bfloat16* gmul, int M, int N, int K, int ldb)
{
    __shared__ __hip_bfloat16 As[128][32];
    __shared__ __hip_bfloat16 Bs[128][40];

    const int tid  = threadIdx.x;
    const int lane = tid & 63;
    const int wave = tid >> 6;
    const int l15  = lane & 15;
    const int quad = lane >> 4;
    const int q8   = quad * 8;
    const int wm   = wave >> 1;
    const int wn   = wave & 1;
    const int m0   = blockIdx.y * 128;
    const int n0   = blockIdx.x * 128;

    f32x4 acc[4][4];
    const f32x4 zero = {0.f, 0.f, 0.f, 0.f};
#pragma unroll
    for (int i = 0; i < 4; ++i)
#pragma unroll
        for (int j = 0; j < 4; ++j) acc[i][j] = zero;

    const int nK = K >> 5;
    for (int kt = 0; kt < nK; ++kt) {
        const int k0 = kt << 5;
        __syncthreads();
#pragma unroll
        for (int vv = 0; vv < 2; ++vv) {
            const int vi  = vv * 256 + tid;
            const int row = vi >> 2;
            const int col = (vi & 3) * 8;
            *(short8*)(&As[row][col]) =
                *(const short8*)(A + (size_t)(m0 + row) * K + k0 + col);
        }
        {
            const int n  = tid & 127;
            const int kk = tid >> 7;
            const float* bp = Bw + (size_t)k0 * ldb + n0 + n;
#pragma unroll
            for (int p = 0; p < 16; ++p) {
                const int k = p * 2 + kk;
                Bs[n][k] = __float2bfloat16(bp[(size_t)k * ldb]);
            }
        }
        __syncthreads();
        bf16x8 af[4], bfv[4];
#pragma unroll
        for (int mt = 0; mt < 4; ++mt)
            af[mt] = *reinterpret_cast<const bf16x8*>(&As[wm * 64 + mt * 16 + l15][q8]);
#pragma unroll
        for (int nt = 0; nt < 4; ++nt)
            bfv[nt] = *reinterpret_cast<const bf16x8*>(&Bs[wn * 64 + nt * 16 + l15][q8]);
#pragma unroll
        for (int mt = 0; mt < 4; ++mt)
#pragma unroll
            for (int nt = 0; nt < 4; ++nt)
                acc[mt][nt] = __builtin_amdgcn_mfma_f32_16x16x32_bf16(
                    af[mt], bfv[nt], acc[mt][nt], 0, 0, 0);
    }

#pragma unroll
    for (int mt = 0; mt < 4; ++mt) {
#pragma unroll
        for (int nt = 0; nt < 4; ++nt) {
            const f32x4 a  = acc[mt][nt];
            const int col  = n0 + wn * 64 + nt * 16 + l15;
            const int rowb = m0 + wm * 64 + mt * 16 + quad * 4;
#pragma unroll
            for (int r = 0; r < 4; ++r) {
                const size_t idx = (size_t)(rowb + r) * N + col;
                const float val = a[r];
                if constexpr (MODE == 0) {
                    outB[idx] = __float2bfloat16(val);
                } else if constexpr (MODE == 1) {
                    outF[idx] = resid[idx] +
                                __bfloat162float(__float2bfloat16(val));
                } else if constexpr (MODE == 3) {
                    const float g = __bfloat162float(gmul[idx]);
                    const float sil = __bfloat162float(
                        __float2bfloat16(g / (1.f + __expf(-g))));
                    const float u = __bfloat162float(__float2bfloat16(val));
                    outB[idx] = __float2bfloat16(sil * u);
                } else {
                    const __hip_bfloat16 b = __float2bfloat16(val);
                    outB[idx] = b;
                    outF[idx] = __bfloat162float(b);
                }
            }
        }
    }
}

// ---------------- MFMA flash attention: paired q-tiles + reg prefetch --------
// Grid (Tc/128, B*QH): block bx handles q-tiles (31-bx) then (bx) -> uniform
// 33 kt-iterations per block. Next tile's K/V/mask prefetched into registers
// during compute (T14); LDS write happens after the top barrier.
__global__ __launch_bounds__(256) void flash_attn_kernel(
    const __hip_bfloat16* q, const __hip_bfloat16* __restrict__ k,
    const __hip_bfloat16* __restrict__ v, const int* __restrict__ mask,
    __hip_bfloat16* out)
{
    __shared__ unsigned short Ks[64][136];
    __shared__ unsigned short Vs[128][72];
    __shared__ unsigned short Ps[4][16][72];
    __shared__ int msk[64];

    const int tid  = threadIdx.x;
    const int lane = tid & 63;
    const int wave = tid >> 6;
    const int l15  = lane & 15;
    const int quad = lane >> 4;
    const int bh   = blockIdx.y;
    const int b    = bh >> 4;
    const int h    = bh & 15;
    const int kh   = h >> 1;
    const float scale = 0.08838834764831845f;

    // staging geometry (fixed per thread)
    const int skv = tid >> 4;              // K rows: skv + 16*i
    const int sd0 = (tid & 15) * 8;
    const int vkv = tid & 63;              // V row (kv)
    const int vg0 = (tid >> 6) * 4;        // V d-chunk base

    for (int half = 0; half < 2; ++half) {
        const int qt = (half == 0) ? (31 - (int)blockIdx.x) : (int)blockIdx.x;
        const int q0 = qt * 64;

        bf16x8 qf[4];
        {
            const __hip_bfloat16* qp =
                q + (((size_t)(b * Tc + q0 + wave * 16 + l15)) * QHc + h) * Dc;
#pragma unroll
            for (int kk = 0; kk < 4; ++kk)
                qf[kk] = *(const bf16x8*)(qp + kk * 32 + quad * 8);
        }

        float mrow[4] = {MASKVAL, MASKVAL, MASKVAL, MASKVAL};
        float lrow[4] = {0.f, 0.f, 0.f, 0.f};
        f32x4 oacc[8];
#pragma unroll
        for (int i = 0; i < 8; ++i) oacc[i] = (f32x4){0.f, 0.f, 0.f, 0.f};

        // prologue: prefetch tile 0 into registers
        bf16x8 kreg[4];
        short8 vreg[4];
        int mreg = 0;
#pragma unroll
        for (int i = 0; i < 4; ++i)
            kreg[i] = *(const bf16x8*)(
                k + (((size_t)(b * Tc + skv + i * 16)) * KHc + kh) * Dc + sd0);
#pragma unroll
        for (int g = 0; g < 4; ++g)
            vreg[g] = *(const short8*)(
                v + (((size_t)(b * Tc + vkv)) * KHc + kh) * Dc + (vg0 + g) * 8);
        if (tid < 64) mreg = mask[b * Tc + tid];

        const int ktmax = qt;
        for (int kt = 0; kt <= ktmax; ++kt) {
            const int kvbase = kt * 64;
            __syncthreads();                       // LDS free (prev reads done)
            // registers -> LDS
#pragma unroll
            for (int i = 0; i < 4; ++i)
                *(bf16x8*)(&Ks[skv + i * 16][sd0]) = kreg[i];
#pragma unroll
            for (int g = 0; g < 4; ++g) {
                const int d0 = (vg0 + g) * 8;
#pragma unroll
                for (int j = 0; j < 8; ++j)
                    Vs[d0 + j][vkv] = (unsigned short)vreg[g][j];
            }
            if (tid < 64) msk[tid] = mreg;
            __syncthreads();                       // staged tile visible

            // prefetch NEXT tile into registers (hides under compute)
            if (kt < ktmax) {
                const int nb = (kt + 1) * 64;
#pragma unroll
                for (int i = 0; i < 4; ++i)
                    kreg[i] = *(const bf16x8*)(
                        k + (((size_t)(b * Tc + nb + skv + i * 16)) * KHc + kh) * Dc + sd0);
#pragma unroll
                for (int g = 0; g < 4; ++g)
                    vreg[g] = *(const short8*)(
                        v + (((size_t)(b * Tc + nb + vkv)) * KHc + kh) * Dc + (vg0 + g) * 8);
                if (tid < 64) mreg = mask[b * Tc + nb + tid];
            }

            // ---- QK^T -------------------------------------------------------
            f32x4 sacc[4];
#pragma unroll
            for (int nt = 0; nt < 4; ++nt) sacc[nt] = (f32x4){0.f, 0.f, 0.f, 0.f};
            __builtin_amdgcn_s_setprio(1);
#pragma unroll
            for (int nt = 0; nt < 4; ++nt)
#pragma unroll
                for (int kk = 0; kk < 4; ++kk) {
                    const bf16x8 kf = *(const bf16x8*)(&Ks[nt * 16 + l15][kk * 32 + quad * 8]);
                    sacc[nt] = __builtin_amdgcn_mfma_f32_16x16x32_bf16(
                        qf[kk], kf, sacc[nt], 0, 0, 0);
                }
            __builtin_amdgcn_s_setprio(0);

            // ---- online softmax --------------------------------------------
            float tmax[4] = {MASKVAL, MASKVAL, MASKVAL, MASKVAL};
#pragma unroll
            for (int nt = 0; nt < 4; ++nt) {
                const int kvpos  = kvbase + nt * 16 + l15;
                const bool kvld  = (msk[nt * 16 + l15] != 0);
#pragma unroll
                for (int r = 0; r < 4; ++r) {
                    const int qr = q0 + wave * 16 + quad * 4 + r;
                    float s = sacc[nt][r] * scale;
                    s = (kvld && kvpos <= qr) ? s : MASKVAL;
                    sacc[nt][r] = s;
                    tmax[r] = fmaxf(tmax[r], s);
                }
            }
#pragma unroll
            for (int r = 0; r < 4; ++r)
                for (int off = 1; off < 16; off <<= 1)
                    tmax[r] = fmaxf(tmax[r], __shfl_xor(tmax[r], off, 64));

            float alpha[4];
#pragma unroll
            for (int r = 0; r < 4; ++r) {
                const float mnew = fmaxf(mrow[r], tmax[r]);
                alpha[r] = __expf(mrow[r] - mnew);
                mrow[r]  = mnew;
            }
            float tsum[4] = {0.f, 0.f, 0.f, 0.f};
#pragma unroll
            for (int nt = 0; nt < 4; ++nt)
#pragma unroll
                for (int r = 0; r < 4; ++r) {
                    const float p = __expf(sacc[nt][r] - mrow[r]);
                    sacc[nt][r] = p;
                    tsum[r] += p;
                }
#pragma unroll
            for (int r = 0; r < 4; ++r)
                for (int off = 1; off < 16; off <<= 1)
                    tsum[r] += __shfl_xor(tsum[r], off, 64);
#pragma unroll
            for (int r = 0; r < 4; ++r)
                lrow[r] = lrow[r] * alpha[r] + tsum[r];

            // P -> LDS (per-wave slab; no cross-wave dep -> no barrier needed)
#pragma unroll
            for (int nt = 0; nt < 4; ++nt)
#pragma unroll
                for (int r = 0; r < 4; ++r) {
                    const __hip_bfloat16 pb = __float2bfloat16(sacc[nt][r]);
                    Ps[wave][quad * 4 + r][nt * 16 + l15] =
                        *(const unsigned short*)&pb;
                }

            // ---- PV ---------------------------------------------------------
#pragma unroll
            for (int ntd = 0; ntd < 8; ++ntd)
#pragma unroll
                for (int r = 0; r < 4; ++r) oacc[ntd][r] *= alpha[r];
            bf16x8 pa[2];
#pragma unroll
            for (int kk2 = 0; kk2 < 2; ++kk2)
                pa[kk2] = *(const bf16x8*)(&Ps[wave][l15][kk2 * 32 + quad * 8]);
            __builtin_amdgcn_s_setprio(1);
#pragma unroll
            for (int ntd = 0; ntd < 8; ++ntd)
#pragma unroll
                for (int kk2 = 0; kk2 < 2; ++kk2) {
                    const bf16x8 vf = *(const bf16x8*)(
                        &Vs[ntd * 16 + l15][kk2 * 32 + quad * 8]);
                    oacc[ntd] = __builtin_amdgcn_mfma_f32_16x16x32_bf16(
                        pa[kk2], vf, oacc[ntd], 0, 0, 0);
                }
            __builtin_amdgcn_s_setprio(0);
        }

        // ---- epilogue for this q-tile --------------------------------------
#pragma unroll
        for (int ntd = 0; ntd < 8; ++ntd)
#pragma unroll
            for (int r = 0; r < 4; ++r) {
                const float li = lrow[r];
                const float o  = (li > 0.f) ? oacc[ntd][r] / li : 0.f;
                const int qr   = q0 + wave * 16 + quad * 4 + r;
                out[(((size_t)(b * Tc + qr)) * QHc + h) * Dc + ntd * 16 + l15] =
                    __float2bfloat16(o);
            }
    }
}

// ---------------------------------------------------------------------------
extern "C" void kernel_launch(void* const* d_in, const int* in_sizes, int n_in,
                              void* d_out, int out_size, void* d_ws, size_t ws_size,
                              hipStream_t stream) {
    const float* x          = (const float*)d_in[0];
    const float* sinp       = (const float*)d_in[1];
    const float* cosp       = (const float*)d_in[2];
    const int*   token_mask = (const int*)d_in[3];
    const float* pre_gamma  = (const float*)d_in[5];
    const float* wq         = (const float*)d_in[6];
    const float* wk         = (const float*)d_in[7];
    const float* wv         = (const float*)d_in[8];
    const float* q_gamma    = (const float*)d_in[9];
    const float* k_gamma    = (const float*)d_in[10];
    const float* wo         = (const float*)d_in[11];
    const float* post_gamma = (const float*)d_in[12];
    const float* wg         = (const float*)d_in[13];
    const float* wu         = (const float*)d_in[14];
    const float* wd         = (const float*)d_in[15];

    // d_out sections, ALL FLOAT32: x | k | v
    float* outx = (float*)d_out;
    float* outk = outx + (size_t)Bc * Tc * Hc;
    float* outv = outk + (size_t)Bc * Tc * KHc * Dc;

    const bool fast = (ws_size >= 176160768ull);

    if (fast) {
        // ---- fast path: bf16 transposed weights in ws -----------------------
        char* w = (char*)d_ws;
        __hip_bfloat16* wq_t  = (__hip_bfloat16*)(w);               //  8.39 MB
        __hip_bfloat16* wk_t  = (__hip_bfloat16*)(w + 8388608);     //  4.19 MB
        __hip_bfloat16* wv_t  = (__hip_bfloat16*)(w + 12582912);    //  4.19 MB
        __hip_bfloat16* wo_t  = (__hip_bfloat16*)(w + 16777216);    //  8.39 MB
        __hip_bfloat16* wg_t  = (__hip_bfloat16*)(w + 25165824);    // 33.55 MB
        __hip_bfloat16* wu_t  = (__hip_bfloat16*)(w + 58720256);    // 33.55 MB
        __hip_bfloat16* wd_t  = (__hip_bfloat16*)(w + 92274688);    // 33.55 MB
        __hip_bfloat16* xnorm = (__hip_bfloat16*)(w + 125829120);   // 16.78 MB
        __hip_bfloat16* qbuf  = (__hip_bfloat16*)(w + 142606336);   // 16.78 MB
        __hip_bfloat16* kbuf  = (__hip_bfloat16*)(w + 159383552);   //  8.39 MB
        __hip_bfloat16* vbuf  = (__hip_bfloat16*)(w + 167772160);   //  8.39 MB
        // qbuf|kbuf|vbuf contiguous (33.55 MB); free after attention+wo
        __hip_bfloat16* Gbig  = qbuf;

        // 0. convert+transpose all weights (f32 [K][N] -> bf16 [N][K])
        convert_transpose_kernel<<<dim3(Hc/32, Hc/32), 256, 0, stream>>>(wq, wq_t, Hc, Hc);
        convert_transpose_kernel<<<dim3((KHc*Dc)/32, Hc/32), 256, 0, stream>>>(wk, wk_t, Hc, KHc*Dc);
        convert_transpose_kernel<<<dim3((KHc*Dc)/32, Hc/32), 256, 0, stream>>>(wv, wv_t, Hc, KHc*Dc);
        convert_transpose_kernel<<<dim3(Hc/32, Hc/32), 256, 0, stream>>>(wo, wo_t, Hc, Hc);
        convert_transpose_kernel<<<dim3(Fc/32, Hc/32), 256, 0, stream>>>(wg, wg_t, Hc, Fc);
        convert_transpose_kernel<<<dim3(Fc/32, Hc/32), 256, 0, stream>>>(wu, wu_t, Hc, Fc);
        convert_transpose_kernel<<<dim3(Hc/32, Fc/32), 256, 0, stream>>>(wd, wd_t, Fc, Hc);

        // 1. pre-RMSNorm
        rmsnorm_f32_kernel<<<Mc, 256, 0, stream>>>(x, pre_gamma, xnorm, Hc);

        // 2. fused QKV projection: Bt = [wq_t|wk_t|wv_t] = [4096][2048],
        //    outputs split in epilogue (qbuf / kbuf / vbuf+outv)
        gemm256_kernel<5><<<dim3(4096/256, Mc/256), 512, 0, stream>>>(
            xnorm, wq_t, qbuf, outv, nullptr, nullptr, Mc, 4096, Hc, Hc, Hc, 0);

        // 3-4. per-head RMSNorm + RoPE
        qknorm_rope_kernel<<<Mc*QHc, 128, 0, stream>>>(
            qbuf, q_gamma, sinp, cosp, qbuf, nullptr, QHc);
        qknorm_rope_kernel<<<Mc*KHc, 128, 0, stream>>>(
            kbuf, k_gamma, sinp, cosp, kbuf, outk, KHc);

        // 5. MFMA flash attention (paired q-tiles: grid.x = Tc/128)
        flash_attn_kernel<<<dim3(Tc/128, Bc*QHc), 256, 0, stream>>>(
            qbuf, kbuf, vbuf, token_mask, qbuf);

        // 6. wo projection + residual -> outx
        gemm256_kernel<1><<<dim3(Hc/256, Mc/256), 512, 0, stream>>>(
            qbuf, wo_t, nullptr, outx, x, nullptr, Mc, Hc, Hc, Hc, Hc, Hc);

        // 7. post-RMSNorm
        rmsnorm_f32_kernel<<<Mc, 256, 0, stream>>>(outx, post_gamma, xnorm, Hc);

        // 8. MLP in 2 half-F passes of 4096; wd via split-K=2 atomics (grid.z)
        for (int hh = 0; hh < 2; ++hh) {
            const __hip_bfloat16* wg_h = wg_t + (size_t)hh * 4096 * Hc;
            const __hip_bfloat16* wu_h = wu_t + (size_t)hh * 4096 * Hc;
            const __hip_bfloat16* wd_h = wd_t + (size_t)hh * 4096;   // k-cols
            gemm256_kernel<0><<<dim3(4096/256, Mc/256), 512, 0, stream>>>(
                xnorm, wg_h, Gbig, nullptr, nullptr, nullptr,
                Mc, 4096, Hc, Hc, Hc, 4096);
            gemm256_kernel<3><<<dim3(4096/256, Mc/256), 512, 0, stream>>>(
                xnorm, wu_h, Gbig, nullptr, nullptr, Gbig,
                Mc, 4096, Hc, Hc, Hc, 4096);
            gemm256_kernel<2><<<dim3(Hc/256, Mc/256, 2), 512, 0, stream>>>(
                Gbig, wd_h, nullptr, outx, nullptr, nullptr,
                Mc, Hc, 2048, 4096, Fc, Hc);
        }
    } else {
        // ---- fallback: f32-weight path (48 MB ws) ---------------------------
        char* w = (char*)d_ws;
        __hip_bfloat16* xnorm = (__hip_bfloat16*)(w);
        __hip_bfloat16* qbuf  = (__hip_bfloat16*)(w + 16777216);
        __hip_bfloat16* kbuf  = (__hip_bfloat16*)(w + 33554432);
        __hip_bfloat16* vbuf  = (__hip_bfloat16*)(w + 41943040);
        __hip_bfloat16* Gtmp  = qbuf;

        rmsnorm_f32_kernel<<<Mc, 256, 0, stream>>>(x, pre_gamma, xnorm, Hc);
        gemm_kernel<0><<<dim3(Hc/128, Mc/128), 256, 0, stream>>>(
            xnorm, wq, qbuf, nullptr, nullptr, nullptr, Mc, Hc, Hc, Hc);
        gemm_kernel<0><<<dim3((KHc*Dc)/128, Mc/128), 256, 0, stream>>>(
            xnorm, wk, kbuf, nullptr, nullptr, nullptr, Mc, KHc*Dc, Hc, KHc*Dc);
        gemm_kernel<4><<<dim3((KHc*Dc)/128, Mc/128), 256, 0, stream>>>(
            xnorm, wv, vbuf, outv, nullptr, nullptr, Mc, KHc*Dc, Hc, KHc*Dc);
        qknorm_rope_kernel<<<Mc*QHc, 128, 0, stream>>>(
            qbuf, q_gamma, sinp, cosp, qbuf, nullptr, QHc);
        qknorm_rope_kernel<<<Mc*KHc, 128, 0, stream>>>(
            kbuf, k_gamma, sinp, cosp, kbuf, outk, KHc);
        flash_attn_kernel<<<dim3(Tc/128, Bc*QHc), 256, 0, stream>>>(
            qbuf, kbuf, vbuf, token_mask, qbuf);
        gemm_kernel<1><<<dim3(Hc/128, Mc/128), 256, 0, stream>>>(
            qbuf, wo, nullptr, outx, x, nullptr, Mc, Hc, Hc, Hc);
        rmsnorm_f32_kernel<<<Mc, 256, 0, stream>>>(outx, post_gamma, xnorm, Hc);
        for (int c = 0; c < 4; ++c) {
            const float* wg_c = wg + (size_t)c * FCHUNK;
            const float* wu_c = wu + (size_t)c * FCHUNK;
            const float* wd_c = wd + (size_t)c * FCHUNK * Hc;
            gemm_kernel<0><<<dim3(FCHUNK/128, Mc/128), 256, 0, stream>>>(
                xnorm, wg_c, Gtmp, nullptr, nullptr, nullptr, Mc, FCHUNK, Hc, Fc);
            gemm_kernel<3><<<dim3(FCHUNK/128, Mc/128), 256, 0, stream>>>(
                xnorm, wu_c, Gtmp, nullptr, nullptr, Gtmp, Mc, FCHUNK, Hc, Fc);
            gemm_kernel<1><<<dim3(Hc/128, Mc/128), 256, 0, stream>>>(
                Gtmp, wd_c, nullptr, outx, outx, nullptr, Mc, Hc, FCHUNK, Hc);
        }
    }
}

// Round 4
// 1127.778 us; speedup vs baseline: 5.3309x; 1.0332x over previous
//
#include <hip/hip_runtime.h>
#include <hip/hip_bf16.h>

// ---------------------------------------------------------------------------
// Transformer block on MI355X. B=2, T=2048, H=2048, QH=16, KH=8, D=128, F=8192
// Outputs concatenated in d_out as FLOAT32: x | k | v
// Round 8 -> 9:
//  * gemm256: bijective XCD swizzle (m204) on flattened (x,y) id -> each XCD
//    gets a contiguous work chunk (A-panel L2 locality). All grids %8==0.
//  * flash_attn: V pre-transposed ONCE into vtbuf[kh*128+d][Mc] (overlaid on
//    wk_t|wv_t, dead after fused QKV gemm). V staging = 4 coalesced bf16x8
//    loads + 4 ds_write_b128 per thread, replacing 32 scalar extracts +
//    32 ds_write_b16 per tile. PV read layout unchanged. Template<VT> keeps
//    the old path for the fallback ws layout.
//  * weight converts batched 7 -> 4 launches (blockIdx.z picks pair member).
// gemm256 ledger unchanged (round-7 comment in git history).
// ---------------------------------------------------------------------------

#define Bc  2
#define Tc  2048
#define Hc  2048
#define QHc 16
#define KHc 8
#define Dc  128
#define Fc  8192
#define Mc  (Bc*Tc)          // 4096 rows
#define FCHUNK 2048          // fallback MLP F-chunk
#define EPSc 1e-6f
#define MASKVAL (-1e30f)

typedef __bf16  bf16x8 __attribute__((ext_vector_type(8)));
typedef short   short8 __attribute__((ext_vector_type(8)));
typedef float   f32x4  __attribute__((ext_vector_type(4)));

// ---------------- reductions -------------------------------------------------
__device__ __forceinline__ float waveReduceSum(float v) {
    for (int off = 32; off > 0; off >>= 1) v += __shfl_down(v, off, 64);
    return v;
}

// ---------------- async global->LDS 16B helper -------------------------------
__device__ __forceinline__ void load_lds_16(const __hip_bfloat16* g,
                                            __hip_bfloat16* l) {
    __builtin_amdgcn_global_load_lds(
        (const __attribute__((address_space(1))) void*)g,
        (__attribute__((address_space(3))) void*)l, 16, 0, 0);
}

// ---------------- RMSNorm over f32 rows -> bf16 ------------------------------
__global__ __launch_bounds__(256) void rmsnorm_f32_kernel(
    const float* __restrict__ in, const float* __restrict__ gamma,
    __hip_bfloat16* __restrict__ out, int width)
{
    const int row = blockIdx.x;
    const float* r = in + (size_t)row * width;
    float ss = 0.f;
    for (int i = threadIdx.x; i < width; i += 256) { float v = r[i]; ss += v * v; }
    ss = waveReduceSum(ss);
    __shared__ float red[4];
    if ((threadIdx.x & 63) == 0) red[threadIdx.x >> 6] = ss;
    __syncthreads();
    const float tot = red[0] + red[1] + red[2] + red[3];
    const float inv = 1.0f / sqrtf(tot / (float)width + EPSc);
    __hip_bfloat16* o = out + (size_t)row * width;
    for (int i = threadIdx.x; i < width; i += 256)
        o[i] = __float2bfloat16(gamma[i] * r[i] * inv);
}

// ---------------- fused per-head RMSNorm (D=128) + RoPE ----------------------
__global__ __launch_bounds__(128) void qknorm_rope_kernel(
    const __hip_bfloat16* in, const float* __restrict__ gamma,
    const float* __restrict__ sinp, const float* __restrict__ cosp,
    __hip_bfloat16* outB, float* outF, int heads)
{
    const int row = blockIdx.x;            // (b*T + t)*heads + h
    const int bt  = row / heads;           // b*T + t
    const int d   = threadIdx.x;           // 0..127
    const float v = __bfloat162float(in[(size_t)row * Dc + d]);
    float ss = waveReduceSum(v * v);
    __shared__ float red[2];
    __shared__ float nrm[Dc];
    if ((d & 63) == 0) red[d >> 6] = ss;
    __syncthreads();
    const float rms = sqrtf((red[0] + red[1]) * (1.0f / (float)Dc) + EPSc);
    const float xn = __bfloat162float(__float2bfloat16(gamma[d] * v / rms));
    nrm[d] = xn;
    __syncthreads();
    float res;
    if (d < 64) {
        const float s = sinp[(size_t)bt * 64 + d];
        const float c = cosp[(size_t)bt * 64 + d];
        res = nrm[d] * c - nrm[d + 64] * s;
    } else {
        const float s = sinp[(size_t)bt * 64 + (d - 64)];
        const float c = cosp[(size_t)bt * 64 + (d - 64)];
        res = nrm[d] * c + nrm[d - 64] * s;
    }
    outB[(size_t)row * Dc + d] = __float2bfloat16(res);
    if (outF) outF[(size_t)row * Dc + d] = res;   // un-rounded f32 (ref k dtype)
}

// ---------------- weight convert+transpose (z-batched pair) ------------------
// W f32[K][N] -> Wt bf16[N][K]; blockIdx.z selects (W0,Wt0) or (W1,Wt1).
__global__ __launch_bounds__(256) void convert_transpose2_kernel(
    const float* __restrict__ W0, __hip_bfloat16* __restrict__ Wt0,
    const float* __restrict__ W1, __hip_bfloat16* __restrict__ Wt1,
    int K, int N)
{
    const float* W = blockIdx.z ? W1 : W0;
    __hip_bfloat16* Wt = blockIdx.z ? Wt1 : Wt0;
    __shared__ float tile[32][33];
    const int tx = threadIdx.x & 31;
    const int ty = threadIdx.x >> 5;       // 0..7
    const int n0 = blockIdx.x * 32;
    const int k0 = blockIdx.y * 32;
    for (int r = 0; r < 4; ++r) {
        const int k = ty + r * 8;
        tile[k][tx] = W[(size_t)(k0 + k) * N + n0 + tx];
    }
    __syncthreads();
    for (int r = 0; r < 4; ++r) {
        const int n = ty + r * 8;
        Wt[(size_t)(n0 + n) * K + k0 + tx] = __float2bfloat16(tile[tx][n]);
    }
}

// ---------------- bf16 transpose: in[R][C] -> out[C][R] ----------------------
__global__ __launch_bounds__(256) void transpose_bf16_kernel(
    const __hip_bfloat16* __restrict__ in, __hip_bfloat16* __restrict__ out,
    int R, int C)
{
    __shared__ __hip_bfloat16 tile[32][33];
    const int tx = threadIdx.x & 31;
    const int ty = threadIdx.x >> 5;       // 0..7
    const int c0 = blockIdx.x * 32;
    const int r0 = blockIdx.y * 32;
    for (int i = 0; i < 4; ++i)
        tile[ty + i * 8][tx] = in[(size_t)(r0 + ty + i * 8) * C + c0 + tx];
    __syncthreads();
    for (int i = 0; i < 4; ++i)
        out[(size_t)(c0 + ty + i * 8) * R + r0 + tx] = tile[tx][ty + i * 8];
}

// ============================================================================
// 256x256 8-phase GEMM. C[M,N] = A[M,K](bf16) @ Bt[N,K]^T (bf16).
// 512 threads = 8 waves (2 wm x 4 wn); per-wave 128x64 out; BK=64, 2 tiles/iter.
// LDS 128KB: As[2][256][64] | Bs[2][256][64], chunk-XOR swizzled.
// MODE: 0 bf16 out; 1 f32 resid+bf16(acc); 2 split-K f32 atomic into outF
//       (grid.z slices of depth K); 3 silu-mul; 4 dual; 5 fused-QKV split.
// XCD swizzle: work id = (orig&7)*(nwg/8) + (orig>>3)  [nwg%8==0 always].
// ============================================================================

__device__ __forceinline__ void stage_unitA256(
    const __hip_bfloat16* __restrict__ Ag, __hip_bfloat16* bufBase,
    int m0, int lda, int kk0, int h, int tid)
{
#pragma unroll
    for (int p = 0; p < 2; ++p) {
        const int ci = p * 512 + tid;          // 0..1023 chunks of 16B
        const int rl = ci >> 3;                // local row 0..127
        const int cc = ci & 7;                 // dest chunk (linear)
        const int grow = m0 + ((rl >> 6) * 128) + h * 64 + (rl & 63);
        const int scc = cc ^ (rl & 7);         // pre-swizzled source chunk
        load_lds_16(Ag + (size_t)grow * lda + kk0 + scc * 8,
                    bufBase + h * 8192 + ci * 8);
    }
}

__device__ __forceinline__ void stage_unitB256(
    const __hip_bfloat16* __restrict__ Bg, __hip_bfloat16* bufBase,
    int n0, int ldt, int kk0, int h, int tid)
{
#pragma unroll
    for (int p = 0; p < 2; ++p) {
        const int ci = p * 512 + tid;
        const int rl = ci >> 3;
        const int cc = ci & 7;
        const int grow = n0 + h * 128 + rl;
        const int scc = cc ^ (rl & 7);
        load_lds_16(Bg + (size_t)grow * ldt + kk0 + scc * 8,
                    bufBase + h * 8192 + ci * 8);
    }
}

__device__ __forceinline__ bf16x8 read_frag256(const __hip_bfloat16* buf,
                                               int r, int w)
{
    const int cc = w ^ (r & 7);                // swizzled read
    return *reinterpret_cast<const bf16x8*>(buf + r * 64 + cc * 8);
}

template <int MODE>
__global__ __launch_bounds__(512, 2) void gemm256_kernel(
    const __hip_bfloat16* __restrict__ A, const __hip_bfloat16* __restrict__ Bt,
    __hip_bfloat16* outB, float* outF, const float* resid,
    const __hip_bfloat16* gmul, int M, int N, int K, int lda, int ldt, int ldc)
{
    __shared__ __hip_bfloat16 smem[65536];     // 128 KB
    __hip_bfloat16* Ab0 = smem;
    __hip_bfloat16* Ab1 = smem + 16384;
    __hip_bfloat16* Bb0 = smem + 32768;
    __hip_bfloat16* Bb1 = smem + 49152;

    if constexpr (MODE == 2) {                 // split-K slice along k
        A  += (size_t)blockIdx.z * K;
        Bt += (size_t)blockIdx.z * K;
    }

    // ---- bijective XCD swizzle over (x,y); nwg % 8 == 0 for all launches ----
    const int nwg  = gridDim.x * gridDim.y;
    const int orig = blockIdx.y * gridDim.x + blockIdx.x;
    const int swz  = (orig & 7) * (nwg >> 3) + (orig >> 3);
    const int bxs  = swz % gridDim.x;
    const int bys  = swz / gridDim.x;

    const int tid  = threadIdx.x;
    const int lane = tid & 63;
    const int wave = tid >> 6;
    const int l15  = lane & 15;
    const int quad = lane >> 4;
    const int wm   = wave >> 2;                // 0..1
    const int wn   = wave & 3;                 // 0..3
    const int m0   = bys * 256;
    const int n0   = bxs * 256;
    const int NTt  = K >> 6;                   // 64-wide K tiles (even)

    f32x4 acc[8][4];
    const f32x4 zero = {0.f, 0.f, 0.f, 0.f};
#pragma unroll
    for (int i = 0; i < 8; ++i)
#pragma unroll
        for (int j = 0; j < 4; ++j) acc[i][j] = zero;

    // ---- prologue: tile0 fully, tile1 except A-unit1 (staged at Ph1) --------
    stage_unitA256(A, Ab0, m0, lda, 0, 0, tid);
    stage_unitA256(A, Ab0, m0, lda, 0, 1, tid);
    stage_unitB256(Bt, Bb0, n0, ldt, 0, 0, tid);
    stage_unitB256(Bt, Bb0, n0, ldt, 0, 1, tid);
    if (NTt > 1) {
        stage_unitA256(A, Ab1, m0, lda, 64, 0, tid);
        stage_unitB256(Bt, Bb1, n0, ldt, 64, 0, tid);
        stage_unitB256(Bt, Bb1, n0, ldt, 64, 1, tid);
    }
    asm volatile("s_waitcnt vmcnt(0)" ::: "memory");
    asm volatile("s_barrier" ::: "memory");

    bf16x8 bfr[4][2];
    bf16x8 af[4];

#define GB_READ_B(BB)                                                         \
    _Pragma("unroll")                                                         \
    for (int nt = 0; nt < 4; ++nt) {                                          \
        bfr[nt][0] = read_frag256(BB, wn * 64 + nt * 16 + l15, quad);         \
        bfr[nt][1] = read_frag256(BB, wn * 64 + nt * 16 + l15, 4 + quad);     \
    }
#define GB_READ_A(AB, MG, KS)                                                 \
    _Pragma("unroll")                                                         \
    for (int mq = 0; mq < 4; ++mq)                                            \
        af[mq] = read_frag256(AB, (MG)*128 + wm * 64 + mq * 16 + l15,         \
                              (KS)*4 + quad);
#define GB_MFMA(MG, KS)                                                       \
    __builtin_amdgcn_s_setprio(1);                                            \
    _Pragma("unroll")                                                         \
    for (int nt = 0; nt < 4; ++nt)                                            \
    _Pragma("unroll")                                                         \
    for (int mq = 0; mq < 4; ++mq)                                            \
        acc[(MG)*4 + mq][nt] = __builtin_amdgcn_mfma_f32_16x16x32_bf16(       \
            af[mq], bfr[nt][KS], acc[(MG)*4 + mq][nt], 0, 0, 0);              \
    __builtin_amdgcn_s_setprio(0);
#define SBAR256 asm volatile("s_barrier" ::: "memory")
#define VMC6    asm volatile("s_waitcnt vmcnt(6)" ::: "memory")

    const int nIter = NTt >> 1;
    for (int it = 0; it < nIter; ++it) {
        const int t1 = 2 * it + 1, t2 = 2 * it + 2, t3 = 2 * it + 3;
        // Ph1: compute t0 mg0 ks0; stage A1(t1) -> buf1.u1
        GB_READ_B(Bb0); GB_READ_A(Ab0, 0, 0);
        stage_unitA256(A, Ab1, m0, lda, t1 * 64, 1, tid);
        SBAR256; GB_MFMA(0, 0); SBAR256;
        // Ph2: t0 mg0 ks1; stage B0(t2)
        GB_READ_A(Ab0, 0, 1);
        if (t2 < NTt) stage_unitB256(Bt, Bb0, n0, ldt, t2 * 64, 0, tid);
        SBAR256; GB_MFMA(0, 1); SBAR256;
        // Ph3: t0 mg1 ks0; stage B1(t2)
        GB_READ_A(Ab0, 1, 0);
        if (t2 < NTt) stage_unitB256(Bt, Bb0, n0, ldt, t2 * 64, 1, tid);
        SBAR256; GB_MFMA(1, 0); SBAR256;
        // Ph4: t0 mg1 ks1; stage A0(t2); GATE vmcnt(6)
        GB_READ_A(Ab0, 1, 1);
        if (t2 < NTt) stage_unitA256(A, Ab0, m0, lda, t2 * 64, 0, tid);
        SBAR256; GB_MFMA(1, 1); VMC6; SBAR256;
        // Ph5: t1 mg0 ks0; stage A1(t2)
        GB_READ_B(Bb1); GB_READ_A(Ab1, 0, 0);
        if (t2 < NTt) stage_unitA256(A, Ab0, m0, lda, t2 * 64, 1, tid);
        SBAR256; GB_MFMA(0, 0); SBAR256;
        // Ph6: t1 mg0 ks1; stage B0(t3)
        GB_READ_A(Ab1, 0, 1);
        if (t3 < NTt) stage_unitB256(Bt, Bb1, n0, ldt, t3 * 64, 0, tid);
        SBAR256; GB_MFMA(0, 1); SBAR256;
        // Ph7: t1 mg1 ks0; stage B1(t3)
        GB_READ_A(Ab1, 1, 0);
        if (t3 < NTt) stage_unitB256(Bt, Bb1, n0, ldt, t3 * 64, 1, tid);
        SBAR256; GB_MFMA(1, 0); SBAR256;
        // Ph8: t1 mg1 ks1; stage A0(t3); GATE vmcnt(6)
        GB_READ_A(Ab1, 1, 1);
        if (t3 < NTt) stage_unitA256(A, Ab1, m0, lda, t3 * 64, 0, tid);
        SBAR256; GB_MFMA(1, 1); VMC6; SBAR256;
    }

#undef GB_READ_B
#undef GB_READ_A
#undef GB_MFMA
#undef SBAR256
#undef VMC6

    // ---- epilogue -----------------------------------------------------------
#pragma unroll
    for (int m = 0; m < 8; ++m) {
#pragma unroll
        for (int nt = 0; nt < 4; ++nt) {
            const f32x4 a  = acc[m][nt];
            const int col  = n0 + wn * 64 + nt * 16 + l15;
            const int rowb = m0 + wm * 128 + (m >> 2) * 64 + (m & 3) * 16 + quad * 4;
#pragma unroll
            for (int r = 0; r < 4; ++r) {
                const size_t idx = (size_t)(rowb + r) * ldc + col;
                const float val = a[r];
                if constexpr (MODE == 0) {
                    outB[idx] = __float2bfloat16(val);
                } else if constexpr (MODE == 1) {
                    outF[idx] = resid[idx] +
                                __bfloat162float(__float2bfloat16(val));
                } else if constexpr (MODE == 2) {
                    unsafeAtomicAdd(&outF[idx], val);   // split-K accumulate
                } else if constexpr (MODE == 3) {
                    const float g = __bfloat162float(gmul[idx]);
                    const float sil = __bfloat162float(
                        __float2bfloat16(g / (1.f + __expf(-g))));
                    const float u = __bfloat162float(__float2bfloat16(val));
                    outB[idx] = __float2bfloat16(sil * u);
                } else if constexpr (MODE == 4) {
                    const __hip_bfloat16 b = __float2bfloat16(val);
                    outB[idx] = b;
                    outF[idx] = __bfloat162float(b);
                } else { // MODE 5: fused QKV. outB=qbuf (k,v contiguous after),
                         // outF=outv. Region is block-uniform (n0 mult of 256).
                    if (n0 < 2048) {
                        outB[(size_t)(rowb + r) * 2048 + col] =
                            __float2bfloat16(val);
                    } else if (n0 < 3072) {
                        outB[8388608 + (size_t)(rowb + r) * 1024 + (col - 2048)] =
                            __float2bfloat16(val);
                    } else {
                        const __hip_bfloat16 b = __float2bfloat16(val);
                        outB[12582912 + (size_t)(rowb + r) * 1024 + (col - 3072)] = b;
                        outF[(size_t)(rowb + r) * 1024 + (col - 3072)] =
                            __bfloat162float(b);
                    }
                }
            }
        }
    }
}

// ---------------- slow-path GEMM (f32 weights) — ws fallback -----------------
template <int MODE>
__global__ __launch_bounds__(256) void gemm_kernel(
    const __hip_bfloat16* __restrict__ A, const float* __restrict__ Bw,
    __hip_bfloat16* outB, float* outF, const float* resid,
    const __hip_bfloat16* gmul, int M, int N, int K, int ldb)
{
    __shared__ __hip_bfloat16 As[128][32];
    __shared__ __hip_bfloat16 Bs[128][40];

    const int tid  = threadIdx.x;
    const int lane = tid & 63;
    const int wave = tid >> 6;
    const int l15  = lane & 15;
    const int quad = lane >> 4;
    const int q8   = quad * 8;
    const int wm   = wave >> 1;
    const int wn   = wave & 1;
    const int m0   = blockIdx.y * 128;
    const int n0   = blockIdx.x * 128;

    f32x4 acc[4][4];
    const f32x4 zero = {0.f, 0.f, 0.f, 0.f};
#pragma unroll
    for (int i = 0; i < 4; ++i)
#pragma unroll
        for (int j = 0; j < 4; ++j) acc[i][j] = zero;

    const int nK = K >> 5;
    for (int kt = 0; kt < nK; ++kt) {
        const int k0 = kt << 5;
        __syncthreads();
#pragma unroll
        for (int vv = 0; vv < 2; ++vv) {
            const int vi  = vv * 256 + tid;
            const int row = vi >> 2;
            const int col = (vi & 3) * 8;
            *(short8*)(&As[row][col]) =
                *(const short8*)(A + (size_t)(m0 + row) * K + k0 + col);
        }
        {
            const int n  = tid & 127;
            const int kk = tid >> 7;
            const float* bp = Bw + (size_t)k0 * ldb + n0 + n;
#pragma unroll
            for (int p = 0; p < 16; ++p) {
                const int k = p * 2 + kk;
                Bs[n][k] = __float2bfloat16(bp[(size_t)k * ldb]);
            }
        }
        __syncthreads();
        bf16x8 af[4], bfv[4];
#pragma unroll
        for (int mt = 0; mt < 4; ++mt)
            af[mt] = *reinterpret_cast<const bf16x8*>(&As[wm * 64 + mt * 16 + l15][q8]);
#pragma unroll
        for (int nt = 0; nt < 4; ++nt)
            bfv[nt] = *reinterpret_cast<const bf16x8*>(&Bs[wn * 64 + nt * 16 + l15][q8]);
#pragma unroll
        for (int mt = 0; mt < 4; ++mt)
#pragma unroll
            for (int nt = 0; nt < 4; ++nt)
                acc[mt][nt] = __builtin_amdgcn_mfma_f32_16x16x32_bf16(
                    af[mt], bfv[nt], acc[mt][nt], 0, 0, 0);
    }

#pragma unroll
    for (int mt = 0; mt < 4; ++mt) {
#pragma unroll
        for (int nt = 0; nt < 4; ++nt) {
            const f32x4 a  = acc[mt][nt];
            const int col  = n0 + wn * 64 + nt * 16 + l15;
            const int rowb = m0 + wm * 64 + mt * 16 + quad * 4;
#pragma unroll
            for (int r = 0; r < 4; ++r) {
                const size_t idx = (size_t)(rowb + r) * N + col;
                const float val = a[r];
                if constexpr (MODE == 0) {
                    outB[idx] = __float2bfloat16(val);
                } else if constexpr (MODE == 1) {
                    outF[idx] = resid[idx] +
                                __bfloat162float(__float2bfloat16(val));
                } else if constexpr (MODE == 3) {
                    const float g = __bfloat162float(gmul[idx]);
                    const float sil = __bfloat162float(
                        __float2bfloat16(g / (1.f + __expf(-g))));
                    const float u = __bfloat162float(__float2bfloat16(val));
                    outB[idx] = __float2bfloat16(sil * u);
                } else {
                    const __hip_bfloat16 b = __float2bfloat16(val);
                    outB[idx] = b;
                    outF[idx] = __bfloat162float(b);
                }
            }
        }
    }
}

// ---------------- MFMA flash attention: paired q-tiles + reg prefetch --------
// Grid (Tc/128, B*QH): block bx handles q-tiles (31-bx) then (bx) -> uniform
// 33 kt-iterations per block. Next tile's K/V/mask prefetched into registers
// during compute (T14); LDS write happens after the top barrier.
// VT=1: v points at vtbuf[kh*128+d][Mc] (pre-transposed) -> vectorized staging.
// VT=0: v is vbuf [bT][kh][d], old scalar-transpose staging (fallback path).
template <int VT>
__global__ __launch_bounds__(256) void flash_attn_kernel(
    const __hip_bfloat16* q, const __hip_bfloat16* __restrict__ k,
    const __hip_bfloat16* __restrict__ v, const int* __restrict__ mask,
    __hip_bfloat16* out)
{
    __shared__ unsigned short Ks[64][136];
    __shared__ unsigned short Vs[128][72];
    __shared__ unsigned short Ps[4][16][72];
    __shared__ int msk[64];

    const int tid  = threadIdx.x;
    const int lane = tid & 63;
    const int wave = tid >> 6;
    const int l15  = lane & 15;
    const int quad = lane >> 4;
    const int bh   = blockIdx.y;
    const int b    = bh >> 4;
    const int h    = bh & 15;
    const int kh   = h >> 1;
    const float scale = 0.08838834764831845f;

    // staging geometry (fixed per thread)
    const int skv = tid >> 4;              // K rows: skv + 16*i
    const int sd0 = (tid & 15) * 8;
    const int vkv = tid & 63;              // VT=0: V row (kv)
    const int vg0 = (tid >> 6) * 4;        // VT=0: V d-chunk base
    const int vd  = tid >> 1;              // VT=1: d row 0..127
    const int vh  = (tid & 1) * 32;        // VT=1: kv half base
    const __hip_bfloat16* vtrow = v + (size_t)(kh * Dc + vd) * Mc + b * Tc;

    for (int half = 0; half < 2; ++half) {
        const int qt = (half == 0) ? (31 - (int)blockIdx.x) : (int)blockIdx.x;
        const int q0 = qt * 64;

        bf16x8 qf[4];
        {
            const __hip_bfloat16* qp =
                q + (((size_t)(b * Tc + q0 + wave * 16 + l15)) * QHc + h) * Dc;
#pragma unroll
            for (int kk = 0; kk < 4; ++kk)
                qf[kk] = *(const bf16x8*)(qp + kk * 32 + quad * 8);
        }

        float mrow[4] = {MASKVAL, MASKVAL, MASKVAL, MASKVAL};
        float lrow[4] = {0.f, 0.f, 0.f, 0.f};
        f32x4 oacc[8];
#pragma unroll
        for (int i = 0; i < 8; ++i) oacc[i] = (f32x4){0.f, 0.f, 0.f, 0.f};

        // prologue: prefetch tile 0 into registers
        bf16x8 kreg[4];
        bf16x8 vregT[4];
        short8 vregS[4];
        int mreg = 0;
#pragma unroll
        for (int i = 0; i < 4; ++i)
            kreg[i] = *(const bf16x8*)(
                k + (((size_t)(b * Tc + skv + i * 16)) * KHc + kh) * Dc + sd0);
        if constexpr (VT) {
#pragma unroll
            for (int j = 0; j < 4; ++j)
                vregT[j] = *(const bf16x8*)(vtrow + vh + j * 8);
        } else {
#pragma unroll
            for (int g = 0; g < 4; ++g)
                vregS[g] = *(const short8*)(
                    v + (((size_t)(b * Tc + vkv)) * KHc + kh) * Dc + (vg0 + g) * 8);
        }
        if (tid < 64) mreg = mask[b * Tc + tid];

        const int ktmax = qt;
        for (int kt = 0; kt <= ktmax; ++kt) {
            const int kvbase = kt * 64;
            __syncthreads();                       // LDS free (prev reads done)
            // registers -> LDS
#pragma unroll
            for (int i = 0; i < 4; ++i)
                *(bf16x8*)(&Ks[skv + i * 16][sd0]) = kreg[i];
            if constexpr (VT) {
#pragma unroll
                for (int j = 0; j < 4; ++j)
                    *(bf16x8*)(&Vs[vd][vh + j * 8]) = vregT[j];
            } else {
#pragma unroll
                for (int g = 0; g < 4; ++g) {
                    const int d0 = (vg0 + g) * 8;
#pragma unroll
                    for (int j = 0; j < 8; ++j)
                        Vs[d0 + j][vkv] = (unsigned short)vregS[g][j];
                }
            }
            if (tid < 64) msk[tid] = mreg;
            __syncthreads();                       // staged tile visible

            // prefetch NEXT tile into registers (hides under compute)
            if (kt < ktmax) {
                const int nb = (kt + 1) * 64;
#pragma unroll
                for (int i = 0; i < 4; ++i)
                    kreg[i] = *(const bf16x8*)(
                        k + (((size_t)(b * Tc + nb + skv + i * 16)) * KHc + kh) * Dc + sd0);
                if constexpr (VT) {
#pragma unroll
                    for (int j = 0; j < 4; ++j)
                        vregT[j] = *(const bf16x8*)(vtrow + nb + vh + j * 8);
                } else {
#pragma unroll
                    for (int g = 0; g < 4; ++g)
                        vregS[g] = *(const short8*)(
                            v + (((size_t)(b * Tc + nb + vkv)) * KHc + kh) * Dc + (vg0 + g) * 8);
                }
                if (tid < 64) mreg = mask[b * Tc + nb + tid];
            }

            // ---- QK^T -------------------------------------------------------
            f32x4 sacc[4];
#pragma unroll
            for (int nt = 0; nt < 4; ++nt) sacc[nt] = (f32x4){0.f, 0.f, 0.f, 0.f};
            __builtin_amdgcn_s_setprio(1);
#pragma unroll
            for (int nt = 0; nt < 4; ++nt)
#pragma unroll
                for (int kk = 0; kk < 4; ++kk) {
                    const bf16x8 kf = *(const bf16x8*)(&Ks[nt * 16 + l15][kk * 32 + quad * 8]);
                    sacc[nt] = __builtin_amdgcn_mfma_f32_16x16x32_bf16(
                        qf[kk], kf, sacc[nt], 0, 0, 0);
                }
            __builtin_amdgcn_s_setprio(0);

            // ---- online softmax --------------------------------------------
            float tmax[4] = {MASKVAL, MASKVAL, MASKVAL, MASKVAL};
#pragma unroll
            for (int nt = 0; nt < 4; ++nt) {
                const int kvpos  = kvbase + nt * 16 + l15;
                const bool kvld  = (msk[nt * 16 + l15] != 0);
#pragma unroll
                for (int r = 0; r < 4; ++r) {
                    const int qr = q0 + wave * 16 + quad * 4 + r;
                    float s = sacc[nt][r] * scale;
                    s = (kvld && kvpos <= qr) ? s : MASKVAL;
                    sacc[nt][r] = s;
                    tmax[r] = fmaxf(tmax[r], s);
                }
            }
#pragma unroll
            for (int r = 0; r < 4; ++r)
                for (int off = 1; off < 16; off <<= 1)
                    tmax[r] = fmaxf(tmax[r], __shfl_xor(tmax[r], off, 64));

            float alpha[4];
#pragma unroll
            for (int r = 0; r < 4; ++r) {
                const float mnew = fmaxf(mrow[r], tmax[r]);
                alpha[r] = __expf(mrow[r] - mnew);
                mrow[r]  = mnew;
            }
            float tsum[4] = {0.f, 0.f, 0.f, 0.f};
#pragma unroll
            for (int nt = 0; nt < 4; ++nt)
#pragma unroll
                for (int r = 0; r < 4; ++r) {
                    const float p = __expf(sacc[nt][r] - mrow[r]);
                    sacc[nt][r] = p;
                    tsum[r] += p;
                }
#pragma unroll
            for (int r = 0; r < 4; ++r)
                for (int off = 1; off < 16; off <<= 1)
                    tsum[r] += __shfl_xor(tsum[r], off, 64);
#pragma unroll
            for (int r = 0; r < 4; ++r)
                lrow[r] = lrow[r] * alpha[r] + tsum[r];

            // P -> LDS (per-wave slab; no cross-wave dep -> no barrier needed)
#pragma unroll
            for (int nt = 0; nt < 4; ++nt)
#pragma unroll
                for (int r = 0; r < 4; ++r) {
                    const __hip_bfloat16 pb = __float2bfloat16(sacc[nt][r]);
                    Ps[wave][quad * 4 + r][nt * 16 + l15] =
                        *(const unsigned short*)&pb;
                }

            // ---- PV ---------------------------------------------------------
#pragma unroll
            for (int ntd = 0; ntd < 8; ++ntd)
#pragma unroll
                for (int r = 0; r < 4; ++r) oacc[ntd][r] *= alpha[r];
            bf16x8 pa[2];
#pragma unroll
            for (int kk2 = 0; kk2 < 2; ++kk2)
                pa[kk2] = *(const bf16x8*)(&Ps[wave][l15][kk2 * 32 + quad * 8]);
            __builtin_amdgcn_s_setprio(1);
#pragma unroll
            for (int ntd = 0; ntd < 8; ++ntd)
#pragma unroll
                for (int kk2 = 0; kk2 < 2; ++kk2) {
                    const bf16x8 vf = *(const bf16x8*)(
                        &Vs[ntd * 16 + l15][kk2 * 32 + quad * 8]);
                    oacc[ntd] = __builtin_amdgcn_mfma_f32_16x16x32_bf16(
                        pa[kk2], vf, oacc[ntd], 0, 0, 0);
                }
            __builtin_amdgcn_s_setprio(0);
        }

        // ---- epilogue for this q-tile --------------------------------------
#pragma unroll
        for (int ntd = 0; ntd < 8; ++ntd)
#pragma unroll
            for (int r = 0; r < 4; ++r) {
                const float li = lrow[r];
                const float o  = (li > 0.f) ? oacc[ntd][r] / li : 0.f;
                const int qr   = q0 + wave * 16 + quad * 4 + r;
                out[(((size_t)(b * Tc + qr)) * QHc + h) * Dc + ntd * 16 + l15] =
                    __float2bfloat16(o);
            }
    }
}

// ---------------------------------------------------------------------------
extern "C" void kernel_launch(void* const* d_in, const int* in_sizes, int n_in,
                              void* d_out, int out_size, void* d_ws, size_t ws_size,
                              hipStream_t stream) {
    const float* x          = (const float*)d_in[0];
    const float* sinp       = (const float*)d_in[1];
    const float* cosp       = (const float*)d_in[2];
    const int*   token_mask = (const int*)d_in[3];
    const float* pre_gamma  = (const float*)d_in[5];
    const float* wq         = (const float*)d_in[6];
    const float* wk         = (const float*)d_in[7];
    const float* wv         = (const float*)d_in[8];
    const float* q_gamma    = (const float*)d_in[9];
    const float* k_gamma    = (const float*)d_in[10];
    const float* wo         = (const float*)d_in[11];
    const float* post_gamma = (const float*)d_in[12];
    const float* wg         = (const float*)d_in[13];
    const float* wu         = (const float*)d_in[14];
    const float* wd         = (const float*)d_in[15];

    // d_out sections, ALL FLOAT32: x | k | v
    float* outx = (float*)d_out;
    float* outk = outx + (size_t)Bc * Tc * Hc;
    float* outv = outk + (size_t)Bc * Tc * KHc * Dc;

    const bool fast = (ws_size >= 176160768ull);

    if (fast) {
        // ---- fast path: bf16 transposed weights in ws -----------------------
        char* w = (char*)d_ws;
        __hip_bfloat16* wq_t  = (__hip_bfloat16*)(w);               //  8.39 MB
        __hip_bfloat16* wk_t  = (__hip_bfloat16*)(w + 8388608);     //  4.19 MB
        __hip_bfloat16* wv_t  = (__hip_bfloat16*)(w + 12582912);    //  4.19 MB
        __hip_bfloat16* wo_t  = (__hip_bfloat16*)(w + 16777216);    //  8.39 MB
        __hip_bfloat16* wg_t  = (__hip_bfloat16*)(w + 25165824);    // 33.55 MB
        __hip_bfloat16* wu_t  = (__hip_bfloat16*)(w + 58720256);    // 33.55 MB
        __hip_bfloat16* wd_t  = (__hip_bfloat16*)(w + 92274688);    // 33.55 MB
        __hip_bfloat16* xnorm = (__hip_bfloat16*)(w + 125829120);   // 16.78 MB
        __hip_bfloat16* qbuf  = (__hip_bfloat16*)(w + 142606336);   // 16.78 MB
        __hip_bfloat16* kbuf  = (__hip_bfloat16*)(w + 159383552);   //  8.39 MB
        __hip_bfloat16* vbuf  = (__hip_bfloat16*)(w + 167772160);   //  8.39 MB
        // vtbuf overlays wk_t|wv_t (dead after fused QKV gemm): 8.39 MB
        __hip_bfloat16* vtbuf = wk_t;
        // qbuf|kbuf|vbuf contiguous (33.55 MB); free after attention+wo
        __hip_bfloat16* Gbig  = qbuf;

        // 0. convert+transpose all weights (f32 [K][N] -> bf16 [N][K]), batched
        convert_transpose2_kernel<<<dim3(Hc/32, Hc/32, 2), 256, 0, stream>>>(
            wq, wq_t, wo, wo_t, Hc, Hc);
        convert_transpose2_kernel<<<dim3((KHc*Dc)/32, Hc/32, 2), 256, 0, stream>>>(
            wk, wk_t, wv, wv_t, Hc, KHc*Dc);
        convert_transpose2_kernel<<<dim3(Fc/32, Hc/32, 2), 256, 0, stream>>>(
            wg, wg_t, wu, wu_t, Hc, Fc);
        convert_transpose2_kernel<<<dim3(Hc/32, Fc/32, 1), 256, 0, stream>>>(
            wd, wd_t, wd, wd_t, Fc, Hc);

        // 1. pre-RMSNorm
        rmsnorm_f32_kernel<<<Mc, 256, 0, stream>>>(x, pre_gamma, xnorm, Hc);

        // 2. fused QKV projection: Bt = [wq_t|wk_t|wv_t] = [4096][2048],
        //    outputs split in epilogue (qbuf / kbuf / vbuf+outv)
        gemm256_kernel<5><<<dim3(4096/256, Mc/256), 512, 0, stream>>>(
            xnorm, wq_t, qbuf, outv, nullptr, nullptr, Mc, 4096, Hc, Hc, Hc, 0);

        // 3. V pre-transpose: vbuf [Mc][KHc*Dc] -> vtbuf [KHc*Dc][Mc]
        //    (wk_t/wv_t are dead from here on)
        transpose_bf16_kernel<<<dim3((KHc*Dc)/32, Mc/32), 256, 0, stream>>>(
            vbuf, vtbuf, Mc, KHc*Dc);

        // 4-5. per-head RMSNorm + RoPE
        qknorm_rope_kernel<<<Mc*QHc, 128, 0, stream>>>(
            qbuf, q_gamma, sinp, cosp, qbuf, nullptr, QHc);
        qknorm_rope_kernel<<<Mc*KHc, 128, 0, stream>>>(
            kbuf, k_gamma, sinp, cosp, kbuf, outk, KHc);

        // 6. MFMA flash attention (paired q-tiles; V from vtbuf)
        flash_attn_kernel<1><<<dim3(Tc/128, Bc*QHc), 256, 0, stream>>>(
            qbuf, kbuf, vtbuf, token_mask, qbuf);

        // 7. wo projection + residual -> outx
        gemm256_kernel<1><<<dim3(Hc/256, Mc/256), 512, 0, stream>>>(
            qbuf, wo_t, nullptr, outx, x, nullptr, Mc, Hc, Hc, Hc, Hc, Hc);

        // 8. post-RMSNorm
        rmsnorm_f32_kernel<<<Mc, 256, 0, stream>>>(outx, post_gamma, xnorm, Hc);

        // 9. MLP in 2 half-F passes of 4096; wd via split-K=2 atomics (grid.z)
        for (int hh = 0; hh < 2; ++hh) {
            const __hip_bfloat16* wg_h = wg_t + (size_t)hh * 4096 * Hc;
            const __hip_bfloat16* wu_h = wu_t + (size_t)hh * 4096 * Hc;
            const __hip_bfloat16* wd_h = wd_t + (size_t)hh * 4096;   // k-cols
            gemm256_kernel<0><<<dim3(4096/256, Mc/256), 512, 0, stream>>>(
                xnorm, wg_h, Gbig, nullptr, nullptr, nullptr,
                Mc, 4096, Hc, Hc, Hc, 4096);
            gemm256_kernel<3><<<dim3(4096/256, Mc/256), 512, 0, stream>>>(
                xnorm, wu_h, Gbig, nullptr, nullptr, Gbig,
                Mc, 4096, Hc, Hc, Hc, 4096);
            gemm256_kernel<2><<<dim3(Hc/256, Mc/256, 2), 512, 0, stream>>>(
                Gbig, wd_h, nullptr, outx, nullptr, nullptr,
                Mc, Hc, 2048, 4096, Fc, Hc);
        }
    } else {
        // ---- fallback: f32-weight path (48 MB ws) ---------------------------
        char* w = (char*)d_ws;
        __hip_bfloat16* xnorm = (__hip_bfloat16*)(w);
        __hip_bfloat16* qbuf  = (__hip_bfloat16*)(w + 16777216);
        __hip_bfloat16* kbuf  = (__hip_bfloat16*)(w + 33554432);
        __hip_bfloat16* vbuf  = (__hip_bfloat16*)(w + 41943040);
        __hip_bfloat16* Gtmp  = qbuf;

        rmsnorm_f32_kernel<<<Mc, 256, 0, stream>>>(x, pre_gamma, xnorm, Hc);
        gemm_kernel<0><<<dim3(Hc/128, Mc/128), 256, 0, stream>>>(
            xnorm, wq, qbuf, nullptr, nullptr, nullptr, Mc, Hc, Hc, Hc);
        gemm_kernel<0><<<dim3((KHc*Dc)/128, Mc/128), 256, 0, stream>>>(
            xnorm, wk, kbuf, nullptr, nullptr, nullptr, Mc, KHc*Dc, Hc, KHc*Dc);
        gemm_kernel<4><<<dim3((KHc*Dc)/128, Mc/128), 256, 0, stream>>>(
            xnorm, wv, vbuf, outv, nullptr, nullptr, Mc, KHc*Dc, Hc, KHc*Dc);
        qknorm_rope_kernel<<<Mc*QHc, 128, 0, stream>>>(
            qbuf, q_gamma, sinp, cosp, qbuf, nullptr, QHc);
        qknorm_rope_kernel<<<Mc*KHc, 128, 0, stream>>>(
            kbuf, k_gamma, sinp, cosp, kbuf, outk, KHc);
        flash_attn_kernel<0><<<dim3(Tc/128, Bc*QHc), 256, 0, stream>>>(
            qbuf, kbuf, vbuf, token_mask, qbuf);
        gemm_kernel<1><<<dim3(Hc/128, Mc/128), 256, 0, stream>>>(
            qbuf, wo, nullptr, outx, x, nullptr, Mc, Hc, Hc, Hc);
        rmsnorm_f32_kernel<<<Mc, 256, 0, stream>>>(outx, post_gamma, xnorm, Hc);
        for (int c = 0; c < 4; ++c) {
            const float* wg_c = wg + (size_t)c * FCHUNK;
            const float* wu_c = wu + (size_t)c * FCHUNK;
            const float* wd_c = wd + (size_t)c * FCHUNK * Hc;
            gemm_kernel<0><<<dim3(FCHUNK/128, Mc/128), 256, 0, stream>>>(
                xnorm, wg_c, Gtmp, nullptr, nullptr, nullptr, Mc, FCHUNK, Hc, Fc);
            gemm_kernel<3><<<dim3(FCHUNK/128, Mc/128), 256, 0, stream>>>(
                xnorm, wu_c, Gtmp, nullptr, nullptr, Gtmp, Mc, FCHUNK, Hc, Fc);
            gemm_kernel<1><<<dim3(Hc/128, Mc/128), 256, 0, stream>>>(
                Gtmp, wd_c, nullptr, outx, outx, nullptr, Mc, Hc, FCHUNK, Hc);
        }
    }
}